// Round 1
// baseline (4366.105 us; speedup 1.0000x reference)
//
#include <hip/hip_runtime.h>
#include <math.h>

#define B_ 2
#define S_ 2048
#define D_ 2048
#define H_ 16
#define QLORA 1536
#define KVLORA 512
#define DN 128
#define DR 64
#define DQK 192
#define DV 128
#define EPSF 1e-6f
#define SCALEF 0.07216878364870322f   // 192^-0.5

// ---------------------------------------------------------------------------
// Generic fp32 GEMM:  C[M,N] = A[M,K] @ W[N,K]^T   (all row-major)
// M,N multiples of 64; K multiple of 16.
// 256 threads, 64x64 tile, each thread computes 4x4.
// ---------------------------------------------------------------------------
#define TBM 64
#define TBN 64
#define TBK 16

__global__ __launch_bounds__(256) void gemm_nt(const float* __restrict__ A,
                                               const float* __restrict__ W,
                                               float* __restrict__ C,
                                               int M, int N, int K) {
    __shared__ float As[TBK][TBM + 4];   // As[k][i], +4 pad keeps float4 alignment
    __shared__ float Ws[TBK][TBN + 4];   // Ws[k][j]

    const int tid = threadIdx.x;
    const int tx = tid & 15;             // 0..15 -> col group
    const int ty = tid >> 4;             // 0..15 -> row group
    const int row0 = blockIdx.y * TBM;
    const int col0 = blockIdx.x * TBN;

    const int lrow = tid >> 2;           // 0..63 (tile row for staging)
    const int lk4  = (tid & 3) * 4;      // 0,4,8,12

    float acc[4][4] = {};

    for (int k0 = 0; k0 < K; k0 += TBK) {
        __syncthreads();
        // stage A tile (64 x 16) : one float4 per thread
        {
            float4 a4 = *(const float4*)&A[(size_t)(row0 + lrow) * K + k0 + lk4];
            As[lk4 + 0][lrow] = a4.x;
            As[lk4 + 1][lrow] = a4.y;
            As[lk4 + 2][lrow] = a4.z;
            As[lk4 + 3][lrow] = a4.w;
        }
        // stage W tile (64 x 16)
        {
            float4 w4 = *(const float4*)&W[(size_t)(col0 + lrow) * K + k0 + lk4];
            Ws[lk4 + 0][lrow] = w4.x;
            Ws[lk4 + 1][lrow] = w4.y;
            Ws[lk4 + 2][lrow] = w4.z;
            Ws[lk4 + 3][lrow] = w4.w;
        }
        __syncthreads();

#pragma unroll
        for (int kk = 0; kk < TBK; ++kk) {
            float4 av = *(const float4*)&As[kk][ty * 4];
            float4 bv = *(const float4*)&Ws[kk][tx * 4];
            float a[4] = {av.x, av.y, av.z, av.w};
            float b[4] = {bv.x, bv.y, bv.z, bv.w};
#pragma unroll
            for (int r = 0; r < 4; ++r)
#pragma unroll
                for (int c = 0; c < 4; ++c)
                    acc[r][c] = fmaf(a[r], b[c], acc[r][c]);
        }
    }

#pragma unroll
    for (int r = 0; r < 4; ++r) {
        float4 v = make_float4(acc[r][0], acc[r][1], acc[r][2], acc[r][3]);
        *(float4*)&C[(size_t)(row0 + ty * 4 + r) * N + col0 + tx * 4] = v;
    }
}

// ---------------------------------------------------------------------------
// RMSNorm in place over rows of length n (n = 1536), blockDim = 256
// ---------------------------------------------------------------------------
__global__ __launch_bounds__(256) void rmsnorm_kernel(float* __restrict__ X,
                                                      const float* __restrict__ w,
                                                      int n) {
    __shared__ float tmp[4];
    const int row = blockIdx.x;
    const int tid = threadIdx.x;
    float* x = X + (size_t)row * n;

    float ss = 0.f;
    for (int c = tid; c < n; c += 256) {
        float v = x[c];
        ss = fmaf(v, v, ss);
    }
#pragma unroll
    for (int off = 32; off; off >>= 1) ss += __shfl_xor(ss, off, 64);
    if ((tid & 63) == 0) tmp[tid >> 6] = ss;
    __syncthreads();
    ss = tmp[0] + tmp[1] + tmp[2] + tmp[3];
    float r = rsqrtf(ss / (float)n + EPSF);

    for (int c = tid; c < n; c += 256) x[c] = x[c] * r * w[c];
}

// ---------------------------------------------------------------------------
// kv post-process: row = b*S+s of kvraw (576 wide).
//   cols 0..511  -> RMSNorm * w -> kvc (compact 512-wide)
//   cols 512..575 -> RoPE        -> kpe (64-wide)
// ---------------------------------------------------------------------------
__global__ __launch_bounds__(256) void kv_post(const float* __restrict__ KV,
                                               const float* __restrict__ w,
                                               const float* __restrict__ fc,
                                               float* __restrict__ kvc,
                                               float* __restrict__ kpe) {
    __shared__ float tmp[4];
    const int row = blockIdx.x;
    const int s = row & (S_ - 1);
    const int tid = threadIdx.x;
    const float* kv = KV + (size_t)row * 576;

    float ss = 0.f;
#pragma unroll
    for (int c = tid; c < KVLORA; c += 256) {
        float v = kv[c];
        ss = fmaf(v, v, ss);
    }
#pragma unroll
    for (int off = 32; off; off >>= 1) ss += __shfl_xor(ss, off, 64);
    if ((tid & 63) == 0) tmp[tid >> 6] = ss;
    __syncthreads();
    ss = tmp[0] + tmp[1] + tmp[2] + tmp[3];
    float r = rsqrtf(ss / (float)KVLORA + EPSF);

#pragma unroll
    for (int c = tid; c < KVLORA; c += 256)
        kvc[(size_t)row * KVLORA + c] = kv[c] * r * w[c];

    if (tid < 32) {
        int i = tid;
        float c0 = fc[(s * 32 + i) * 2 + 0];
        float s0 = fc[(s * 32 + i) * 2 + 1];
        float x0 = kv[KVLORA + 2 * i];
        float x1 = kv[KVLORA + 2 * i + 1];
        kpe[(size_t)row * DR + 2 * i]     = x0 * c0 - x1 * s0;
        kpe[(size_t)row * DR + 2 * i + 1] = x0 * s0 + x1 * c0;
    }
}

// ---------------------------------------------------------------------------
// RoPE on q_pe: q layout (B*S, H, 192), rope cols 128..191 per head, in place
// ---------------------------------------------------------------------------
__global__ __launch_bounds__(256) void q_rope(float* __restrict__ Q,
                                              const float* __restrict__ fc) {
    const int row = blockIdx.x;          // b*S+s
    const int s = row & (S_ - 1);
    const int tid = threadIdx.x;
#pragma unroll
    for (int idx = tid; idx < H_ * 32; idx += 256) {
        int h = idx >> 5;
        int i = idx & 31;
        float c0 = fc[(s * 32 + i) * 2 + 0];
        float s0 = fc[(s * 32 + i) * 2 + 1];
        float* qp = Q + (size_t)row * (H_ * DQK) + h * DQK + DN + 2 * i;
        float x0 = qp[0];
        float x1 = qp[1];
        qp[0] = x0 * c0 - x1 * s0;
        qp[1] = x0 * s0 + x1 * c0;
    }
}

// ---------------------------------------------------------------------------
// Flash attention (causal), fp32.
//   Q   : (B*S, H, 192)  (already roped)
//   KVB : (B*S, H, 256)  [0:128]=k_nope, [128:256]=v
//   KPE : (B*S, 64)      (roped, broadcast over heads)
//   O   : (B*S, H*128)
// Block = 1024 threads = 16 waves; wave w owns q-row qt*16+w for head h.
// K-tile = 32 keys staged in LDS; half-wave g sums half the 192-dim dot.
// ---------------------------------------------------------------------------
#define TQ 16
#define TK 32
#define KPAD 196   // 192+4: float4-aligned, odd/4 stride -> conflict-free

__global__ __launch_bounds__(1024) void flash_attn(const float* __restrict__ Q,
                                                   const float* __restrict__ KVB,
                                                   const float* __restrict__ KPE,
                                                   float* __restrict__ O) {
    __shared__ float Kt[TK][KPAD];
    __shared__ float Vt[TK][DV];
    __shared__ float Qs[TQ][DQK];
    __shared__ float Ps[TQ][TK];

    const int qt = blockIdx.x;
    const int h  = blockIdx.y;
    const int b  = blockIdx.z;
    const int tid = threadIdx.x;
    const int w = tid >> 6;
    const int lane = tid & 63;
    const int g = lane >> 5;         // half-wave id
    const int key = lane & 31;       // key slot within tile
    const int jbase = g * (DQK / 2); // 0 or 96

    const int q_row = qt * TQ + w;   // sequence position of this wave's query

    // stage Q (scaled)
    for (int idx = tid; idx < TQ * DQK; idx += 1024) {
        int r = idx / DQK, c = idx % DQK;
        Qs[r][c] = Q[((size_t)(b * S_ + qt * TQ + r) * H_ + h) * DQK + c] * SCALEF;
    }

    float m = -1e30f, l = 0.f, o0 = 0.f, o1 = 0.f;
    const int n_tiles = (qt * TQ + TQ - 1) / TK + 1;

    for (int kt = 0; kt < n_tiles; ++kt) {
        __syncthreads();
        // stage K tile (32 x 192): k_nope from KVB, k_pe from KPE
        for (int idx = tid; idx < TK * DQK; idx += 1024) {
            int r = idx / DQK, c = idx % DQK;
            int sk = kt * TK + r;
            float v;
            if (c < DN) v = KVB[((size_t)(b * S_ + sk) * H_ + h) * 256 + c];
            else        v = KPE[(size_t)(b * S_ + sk) * DR + (c - DN)];
            Kt[r][c] = v;
        }
        // stage V tile (32 x 128)
        for (int idx = tid; idx < TK * DV; idx += 1024) {
            int r = idx >> 7, c = idx & 127;
            int sk = kt * TK + r;
            Vt[r][c] = KVB[((size_t)(b * S_ + sk) * H_ + h) * 256 + DN + c];
        }
        __syncthreads();

        // score for (q_row, key): half-waves split the 192-dim dot
        float sc = 0.f;
#pragma unroll
        for (int j = 0; j < DQK / 2; j += 4) {
            float4 qv = *(const float4*)&Qs[w][jbase + j];
            float4 kv = *(const float4*)&Kt[key][jbase + j];
            sc = fmaf(qv.x, kv.x, sc);
            sc = fmaf(qv.y, kv.y, sc);
            sc = fmaf(qv.z, kv.z, sc);
            sc = fmaf(qv.w, kv.w, sc);
        }
        sc += __shfl_xor(sc, 32, 64);    // combine halves: full dot in all lanes

        int s_key = kt * TK + key;
        if (s_key > q_row) sc = -1e30f;

        // max over the 32 keys (reduce within each half-wave; halves identical)
        float mt = sc;
#pragma unroll
        for (int off = 16; off; off >>= 1) mt = fmaxf(mt, __shfl_xor(mt, off, 64));
        float m_new = fmaxf(m, mt);
        float alpha = __expf(m - m_new);
        float p = __expf(sc - m_new);
        float ps = p;
#pragma unroll
        for (int off = 16; off; off >>= 1) ps += __shfl_xor(ps, off, 64);
        l = l * alpha + ps;
        m = m_new;
        o0 *= alpha;
        o1 *= alpha;
        Ps[w][key] = p;                  // both halves write identical value
        __syncthreads();

        const int d0 = lane * 2;
#pragma unroll
        for (int kk = 0; kk < TK; ++kk) {
            float pk = Ps[w][kk];
            float2 vv = *(const float2*)&Vt[kk][d0];
            o0 = fmaf(pk, vv.x, o0);
            o1 = fmaf(pk, vv.y, o1);
        }
    }

    float inv_l = 1.f / l;
    float2 res = make_float2(o0 * inv_l, o1 * inv_l);
    *(float2*)&O[(size_t)(b * S_ + q_row) * (H_ * DV) + h * DV + lane * 2] = res;
}

// ---------------------------------------------------------------------------
extern "C" void kernel_launch(void* const* d_in, const int* in_sizes, int n_in,
                              void* d_out, int out_size, void* d_ws, size_t ws_size,
                              hipStream_t stream) {
    const float* x    = (const float*)d_in[0];   // (B,S,D)
    const float* fc   = (const float*)d_in[1];   // (S,32,2)
    const float* Wqa  = (const float*)d_in[2];   // (1536,2048)
    const float* qlw  = (const float*)d_in[3];   // (1536,)
    const float* Wqb  = (const float*)d_in[4];   // (3072,1536)
    const float* Wkva = (const float*)d_in[5];   // (576,2048)
    const float* kvw  = (const float*)d_in[6];   // (512,)
    const float* Wkvb = (const float*)d_in[7];   // (4096,512)
    const float* Wo   = (const float*)d_in[8];   // (2048,2048)
    float* out = (float*)d_out;

    const int M = B_ * S_;                       // 4096 rows
    float* ws = (float*)d_ws;
    float* qlat  = ws;                           // M*1536
    float* kvraw = qlat  + (size_t)M * QLORA;    // M*576
    float* q     = kvraw + (size_t)M * 576;      // M*3072
    float* kvc   = q     + (size_t)M * (H_ * DQK);   // M*512
    float* kpe   = kvc   + (size_t)M * KVLORA;   // M*64
    float* kvb   = kpe   + (size_t)M * DR;       // M*4096
    float* attn  = qlat;                         // reuse: qlat+kvraw dead by then (M*2048)

    // 1) q_lat = x @ Wqa^T ; kv_raw = x @ Wkva^T
    gemm_nt<<<dim3(QLORA / TBN, M / TBM), 256, 0, stream>>>(x, Wqa, qlat, M, QLORA, D_);
    gemm_nt<<<dim3(576 / TBN, M / TBM), 256, 0, stream>>>(x, Wkva, kvraw, M, 576, D_);

    // 2) norms + k_pe rope
    rmsnorm_kernel<<<M, 256, 0, stream>>>(qlat, qlw, QLORA);
    kv_post<<<M, 256, 0, stream>>>(kvraw, kvw, fc, kvc, kpe);

    // 3) q = qlat_n @ Wqb^T ; rope q_pe ; kvb = kvc @ Wkvb^T
    gemm_nt<<<dim3(H_ * DQK / TBN, M / TBM), 256, 0, stream>>>(qlat, Wqb, q, M, H_ * DQK, QLORA);
    q_rope<<<M, 256, 0, stream>>>(q, fc);
    gemm_nt<<<dim3(H_ * 256 / TBN, M / TBM), 256, 0, stream>>>(kvc, Wkvb, kvb, M, H_ * 256, KVLORA);

    // 4) attention
    flash_attn<<<dim3(S_ / TQ, H_, B_), 1024, 0, stream>>>(q, kvb, kpe, attn);

    // 5) out = attn @ Wo^T
    gemm_nt<<<dim3(D_ / TBN, M / TBM), 256, 0, stream>>>(attn, Wo, out, M, D_, D_);
}

// Round 4
// 2230.487 us; speedup vs baseline: 1.9575x; 1.9575x over previous
//
#include <hip/hip_runtime.h>
#include <math.h>

#define B_ 2
#define S_ 2048
#define D_ 2048
#define H_ 16
#define QLORA 1536
#define KVLORA 512
#define DN 128
#define DR 64
#define DQK 192
#define DV 128
#define EPSF 1e-6f
#define SCALEF 0.07216878364870322f   // 192^-0.5

typedef short short8 __attribute__((ext_vector_type(8)));
typedef float float4v __attribute__((ext_vector_type(4)));

__device__ __forceinline__ unsigned short f2bf(float f) {
    union { float f; unsigned u; } x; x.f = f;
    unsigned r = x.u + 0x7fffu + ((x.u >> 16) & 1u);   // RNE
    return (unsigned short)(r >> 16);
}

// ---------------------------------------------------------------------------
// Generic fp32 GEMM:  C[M,N] = A[M,K] @ W[N,K]^T   (row-major)
// ---------------------------------------------------------------------------
#define TBM 64
#define TBN 64
#define TBK 16

__global__ __launch_bounds__(256) void gemm_nt(const float* __restrict__ A,
                                               const float* __restrict__ W,
                                               float* __restrict__ C,
                                               int M, int N, int K) {
    __shared__ float As[TBK][TBM + 4];
    __shared__ float Ws[TBK][TBN + 4];

    const int tid = threadIdx.x;
    const int tx = tid & 15;
    const int ty = tid >> 4;
    const int row0 = blockIdx.y * TBM;
    const int col0 = blockIdx.x * TBN;

    const int lrow = tid >> 2;
    const int lk4  = (tid & 3) * 4;

    float acc[4][4] = {};

    for (int k0 = 0; k0 < K; k0 += TBK) {
        __syncthreads();
        {
            float4 a4 = *(const float4*)&A[(size_t)(row0 + lrow) * K + k0 + lk4];
            As[lk4 + 0][lrow] = a4.x;
            As[lk4 + 1][lrow] = a4.y;
            As[lk4 + 2][lrow] = a4.z;
            As[lk4 + 3][lrow] = a4.w;
        }
        {
            float4 w4 = *(const float4*)&W[(size_t)(col0 + lrow) * K + k0 + lk4];
            Ws[lk4 + 0][lrow] = w4.x;
            Ws[lk4 + 1][lrow] = w4.y;
            Ws[lk4 + 2][lrow] = w4.z;
            Ws[lk4 + 3][lrow] = w4.w;
        }
        __syncthreads();

#pragma unroll
        for (int kk = 0; kk < TBK; ++kk) {
            float4 av = *(const float4*)&As[kk][ty * 4];
            float4 bv = *(const float4*)&Ws[kk][tx * 4];
            float a[4] = {av.x, av.y, av.z, av.w};
            float b[4] = {bv.x, bv.y, bv.z, bv.w};
#pragma unroll
            for (int r = 0; r < 4; ++r)
#pragma unroll
                for (int c = 0; c < 4; ++c)
                    acc[r][c] = fmaf(a[r], b[c], acc[r][c]);
        }
    }

#pragma unroll
    for (int r = 0; r < 4; ++r) {
        float4 v = make_float4(acc[r][0], acc[r][1], acc[r][2], acc[r][3]);
        *(float4*)&C[(size_t)(row0 + ty * 4 + r) * N + col0 + tx * 4] = v;
    }
}

// ---------------------------------------------------------------------------
__global__ __launch_bounds__(256) void rmsnorm_kernel(float* __restrict__ X,
                                                      const float* __restrict__ w,
                                                      int n) {
    __shared__ float tmp[4];
    const int row = blockIdx.x;
    const int tid = threadIdx.x;
    float* x = X + (size_t)row * n;

    float ss = 0.f;
    for (int c = tid; c < n; c += 256) {
        float v = x[c];
        ss = fmaf(v, v, ss);
    }
#pragma unroll
    for (int off = 32; off; off >>= 1) ss += __shfl_xor(ss, off, 64);
    if ((tid & 63) == 0) tmp[tid >> 6] = ss;
    __syncthreads();
    ss = tmp[0] + tmp[1] + tmp[2] + tmp[3];
    float r = rsqrtf(ss / (float)n + EPSF);

    for (int c = tid; c < n; c += 256) x[c] = x[c] * r * w[c];
}

// ---------------------------------------------------------------------------
__global__ __launch_bounds__(256) void kv_post(const float* __restrict__ KV,
                                               const float* __restrict__ w,
                                               const float* __restrict__ fc,
                                               float* __restrict__ kvc,
                                               float* __restrict__ kpe) {
    __shared__ float tmp[4];
    const int row = blockIdx.x;
    const int s = row & (S_ - 1);
    const int tid = threadIdx.x;
    const float* kv = KV + (size_t)row * 576;

    float ss = 0.f;
#pragma unroll
    for (int c = tid; c < KVLORA; c += 256) {
        float v = kv[c];
        ss = fmaf(v, v, ss);
    }
#pragma unroll
    for (int off = 32; off; off >>= 1) ss += __shfl_xor(ss, off, 64);
    if ((tid & 63) == 0) tmp[tid >> 6] = ss;
    __syncthreads();
    ss = tmp[0] + tmp[1] + tmp[2] + tmp[3];
    float r = rsqrtf(ss / (float)KVLORA + EPSF);

#pragma unroll
    for (int c = tid; c < KVLORA; c += 256)
        kvc[(size_t)row * KVLORA + c] = kv[c] * r * w[c];

    if (tid < 32) {
        int i = tid;
        float c0 = fc[(s * 32 + i) * 2 + 0];
        float s0 = fc[(s * 32 + i) * 2 + 1];
        float x0 = kv[KVLORA + 2 * i];
        float x1 = kv[KVLORA + 2 * i + 1];
        kpe[(size_t)row * DR + 2 * i]     = x0 * c0 - x1 * s0;
        kpe[(size_t)row * DR + 2 * i + 1] = x0 * s0 + x1 * c0;
    }
}

// ---------------------------------------------------------------------------
__global__ __launch_bounds__(256) void q_rope(float* __restrict__ Q,
                                              const float* __restrict__ fc) {
    const int row = blockIdx.x;
    const int s = row & (S_ - 1);
    const int tid = threadIdx.x;
#pragma unroll
    for (int idx = tid; idx < H_ * 32; idx += 256) {
        int h = idx >> 5;
        int i = idx & 31;
        float c0 = fc[(s * 32 + i) * 2 + 0];
        float s0 = fc[(s * 32 + i) * 2 + 1];
        float* qp = Q + (size_t)row * (H_ * DQK) + h * DQK + DN + 2 * i;
        float x0 = qp[0];
        float x1 = qp[1];
        qp[0] = x0 * c0 - x1 * s0;
        qp[1] = x0 * s0 + x1 * c0;
    }
}

// ---------------------------------------------------------------------------
// pack_k: Kbf (B,H,S,192) bf16 from kvb (M, H*256) fp32 + kpe (M,64) fp32
// ---------------------------------------------------------------------------
__global__ __launch_bounds__(256) void pack_k(const float* __restrict__ kvb,
                                              const float* __restrict__ kpe,
                                              unsigned short* __restrict__ Kbf) {
    const int c = blockIdx.x * 256 + threadIdx.x;   // chunk of 8 elems
    const int total = B_ * H_ * S_ * (DQK / 8);
    if (c >= total) return;
    const int d8 = c % (DQK / 8);
    const int hs = c / (DQK / 8);
    const int s  = hs % S_;
    const int bh = hs / S_;
    const int b  = bh / H_;
    const int h  = bh % H_;
    const int d  = d8 * 8;
    const int row = b * S_ + s;

    const float* src;
    if (d < DN) src = kvb + (size_t)row * (H_ * 256) + h * 256 + d;
    else        src = kpe + (size_t)row * DR + (d - DN);

    float4 a = *(const float4*)(src);
    float4 bb = *(const float4*)(src + 4);
    union { short8 v; unsigned short u[8]; } t;
    t.u[0] = f2bf(a.x);  t.u[1] = f2bf(a.y);  t.u[2] = f2bf(a.z);  t.u[3] = f2bf(a.w);
    t.u[4] = f2bf(bb.x); t.u[5] = f2bf(bb.y); t.u[6] = f2bf(bb.z); t.u[7] = f2bf(bb.w);
    *(short8*)&Kbf[(size_t)c * 8] = t.v;
}

// ---------------------------------------------------------------------------
// pack_vt: Vt (B,H,128,S) bf16 from kvb (M,H*256) cols h*256+128..+256
// ---------------------------------------------------------------------------
__global__ __launch_bounds__(256) void pack_vt(const float* __restrict__ kvb,
                                               unsigned short* __restrict__ Vt) {
    __shared__ unsigned short T[DV][72];
    const int st = blockIdx.x;            // seq tile (64)
    const int bh = blockIdx.y;            // b*H+h
    const int b = bh >> 4, h = bh & 15;
    const int s0 = st * 64;
    const int tid = threadIdx.x;

    for (int c = tid; c < 64 * 16; c += 256) {
        int sp = c >> 4, ch = c & 15;
        const float* src = kvb + (size_t)(b * S_ + s0 + sp) * (H_ * 256) + h * 256 + DN + ch * 8;
        float4 a = *(const float4*)(src);
        float4 bb = *(const float4*)(src + 4);
        int dv = ch * 8;
        T[dv + 0][sp] = f2bf(a.x);  T[dv + 1][sp] = f2bf(a.y);
        T[dv + 2][sp] = f2bf(a.z);  T[dv + 3][sp] = f2bf(a.w);
        T[dv + 4][sp] = f2bf(bb.x); T[dv + 5][sp] = f2bf(bb.y);
        T[dv + 6][sp] = f2bf(bb.z); T[dv + 7][sp] = f2bf(bb.w);
    }
    __syncthreads();
    for (int c = tid; c < 128 * 8; c += 256) {
        int dv = c >> 3, ch = c & 7;
        *(short8*)&Vt[((size_t)bh * DV + dv) * S_ + s0 + ch * 8] = *(short8*)&T[dv][ch * 8];
    }
}

// ---------------------------------------------------------------------------
// MFMA flash attention (causal), bf16 inputs, fp32 accumulate.
//   Qf  : (B*S, H, 192) fp32  (post-rope; converted to bf16 at frag load)
//   Kbf : (B,H,S,192) bf16
//   Vt  : (B,H,128,S) bf16 (transposed)
//   O   : (B*S, H*128) fp32
// Block = 256 thr = 4 waves; block owns 64 q-rows of one (b,h).
// ---------------------------------------------------------------------------
#define KROW 200    // 192+8 bf16 pad
#define VROW 72     // 64+8
#define PROW 72

__global__ __launch_bounds__(256) void flash_mfma(const float* __restrict__ Qf,
                                                  const unsigned short* __restrict__ Kbf,
                                                  const unsigned short* __restrict__ Vt,
                                                  float* __restrict__ O) {
    __shared__ unsigned short Ks[64][KROW];     // 25600 B
    __shared__ unsigned short Vs[DV][VROW];     // 18432 B
    __shared__ unsigned short Ps[4][16][PROW];  //  9216 B

    const int q0 = blockIdx.x * 64;
    const int h = blockIdx.y, b = blockIdx.z;
    const int tid = threadIdx.x;
    const int w = tid >> 6, lane = tid & 63;
    const int l16 = lane & 15, quad = lane >> 4;

    const size_t bh = (size_t)b * H_ + h;
    const unsigned short* Kg = Kbf + bh * S_ * DQK;
    const unsigned short* Vg = Vt + bh * DV * S_;

    // Q A-frags: rows q0+16w+l16, d = i*32 + quad*8 .. +8
    short8 a_q[6];
    {
        const float* qrow = Qf + (size_t)(b * S_ + q0 + w * 16 + l16) * (H_ * DQK) + h * DQK;
#pragma unroll
        for (int i = 0; i < 6; ++i) {
            const float* p = qrow + i * 32 + quad * 8;
            float4 a = *(const float4*)(p);
            float4 bb = *(const float4*)(p + 4);
            union { short8 v; unsigned short u[8]; } t;
            t.u[0] = f2bf(a.x);  t.u[1] = f2bf(a.y);  t.u[2] = f2bf(a.z);  t.u[3] = f2bf(a.w);
            t.u[4] = f2bf(bb.x); t.u[5] = f2bf(bb.y); t.u[6] = f2bf(bb.z); t.u[7] = f2bf(bb.w);
            a_q[i] = t.v;
        }
    }

    const float4v zf = {0.f, 0.f, 0.f, 0.f};
    float4v o_acc[8] = {zf, zf, zf, zf, zf, zf, zf, zf};
    float m_r[4] = {-1e30f, -1e30f, -1e30f, -1e30f};
    float l_r[4] = {0.f, 0.f, 0.f, 0.f};

    const int ntiles = q0 / 64 + 1;
    for (int kt = 0; kt < ntiles; ++kt) {
        const int kbase = kt * 64;
        __syncthreads();
        // stage K tile: 64 rows x 192 bf16 = 24 short8-chunks per row
        for (int c = tid; c < 64 * 24; c += 256) {
            int r = c / 24, cc = c % 24;
            *(short8*)&Ks[r][cc * 8] =
                *(const short8*)&Kg[(size_t)(kbase + r) * DQK + cc * 8];
        }
        // stage V tile: 128 dv-rows x 64 keys = 8 short8-chunks per row
        for (int c = tid; c < 128 * 8; c += 256) {
            int r = c >> 3, cc = c & 7;
            *(short8*)&Vs[r][cc * 8] =
                *(const short8*)&Vg[(size_t)r * S_ + kbase + cc * 8];
        }
        __syncthreads();

        // QK^T: 4 key-groups x 6 d-chunks
        float4v sc[4] = {zf, zf, zf, zf};
#pragma unroll
        for (int kg = 0; kg < 4; ++kg) {
#pragma unroll
            for (int i = 0; i < 6; ++i) {
                short8 bk = *(const short8*)&Ks[kg * 16 + l16][i * 32 + quad * 8];
                sc[kg] = __builtin_amdgcn_mfma_f32_16x16x32_bf16(a_q[i], bk, sc[kg], 0, 0, 0);
            }
        }

        // softmax (C-layout: row = q0+16w+quad*4+r, col = kbase+kg*16+l16)
        float scv[4][4];
#pragma unroll
        for (int kg = 0; kg < 4; ++kg)
#pragma unroll
            for (int r = 0; r < 4; ++r)
                scv[kg][r] = sc[kg][r] * SCALEF;

        if (kt == ntiles - 1) {
#pragma unroll
            for (int kg = 0; kg < 4; ++kg) {
                int key = kbase + kg * 16 + l16;
#pragma unroll
                for (int r = 0; r < 4; ++r) {
                    int row = q0 + w * 16 + quad * 4 + r;
                    if (key > row) scv[kg][r] = -1e30f;
                }
            }
        }

        float mnew[4];
#pragma unroll
        for (int r = 0; r < 4; ++r) {
            float t = fmaxf(fmaxf(scv[0][r], scv[1][r]), fmaxf(scv[2][r], scv[3][r]));
            t = fmaxf(t, __shfl_xor(t, 1));
            t = fmaxf(t, __shfl_xor(t, 2));
            t = fmaxf(t, __shfl_xor(t, 4));
            t = fmaxf(t, __shfl_xor(t, 8));
            mnew[r] = fmaxf(m_r[r], t);
            float a = __expf(m_r[r] - mnew[r]);
            m_r[r] = mnew[r];
            l_r[r] *= a;
#pragma unroll
            for (int dvt = 0; dvt < 8; ++dvt) o_acc[dvt][r] *= a;
        }

        float psum[4] = {0.f, 0.f, 0.f, 0.f};
#pragma unroll
        for (int kg = 0; kg < 4; ++kg)
#pragma unroll
            for (int r = 0; r < 4; ++r) {
                float p = __expf(scv[kg][r] - mnew[r]);
                psum[r] += p;
                Ps[w][quad * 4 + r][kg * 16 + l16] = f2bf(p);
            }
#pragma unroll
        for (int r = 0; r < 4; ++r) {
            float t = psum[r];
            t += __shfl_xor(t, 1);
            t += __shfl_xor(t, 2);
            t += __shfl_xor(t, 4);
            t += __shfl_xor(t, 8);
            l_r[r] += t;
        }

        // make P writes visible before A-frag reads
        __syncthreads();

        // PV: A = P (rows=l16, k=keys), B = V (k=keys, n=dv)
#pragma unroll
        for (int kc = 0; kc < 2; ++kc) {
            short8 pa = *(const short8*)&Ps[w][l16][kc * 32 + quad * 8];
#pragma unroll
            for (int dvt = 0; dvt < 8; ++dvt) {
                short8 vb = *(const short8*)&Vs[dvt * 16 + l16][kc * 32 + quad * 8];
                o_acc[dvt] = __builtin_amdgcn_mfma_f32_16x16x32_bf16(pa, vb, o_acc[dvt], 0, 0, 0);
            }
        }
    }

    // epilogue
#pragma unroll
    for (int r = 0; r < 4; ++r) {
        float inv = 1.f / l_r[r];
        int row = q0 + w * 16 + quad * 4 + r;
        float* op = O + (size_t)(b * S_ + row) * (H_ * DV) + h * DV;
#pragma unroll
        for (int dvt = 0; dvt < 8; ++dvt)
            op[dvt * 16 + l16] = o_acc[dvt][r] * inv;
    }
}

// ---------------------------------------------------------------------------
extern "C" void kernel_launch(void* const* d_in, const int* in_sizes, int n_in,
                              void* d_out, int out_size, void* d_ws, size_t ws_size,
                              hipStream_t stream) {
    const float* x    = (const float*)d_in[0];
    const float* fc   = (const float*)d_in[1];
    const float* Wqa  = (const float*)d_in[2];
    const float* qlw  = (const float*)d_in[3];
    const float* Wqb  = (const float*)d_in[4];
    const float* Wkva = (const float*)d_in[5];
    const float* kvw  = (const float*)d_in[6];
    const float* Wkvb = (const float*)d_in[7];
    const float* Wo   = (const float*)d_in[8];
    float* out = (float*)d_out;

    const int M = B_ * S_;
    float* ws = (float*)d_ws;
    float* qlat  = ws;                               // M*1536
    float* kvraw = qlat  + (size_t)M * QLORA;        // M*576
    float* kvc   = kvraw + (size_t)M * 576;          // M*512
    float* kpe   = kvc   + (size_t)M * KVLORA;       // M*64
    float* q     = kpe   + (size_t)M * DR;           // M*3072
    float* kvb   = q     + (size_t)M * (H_ * DQK);   // M*4096
    // dead-region reuse:
    unsigned short* Kbf = (unsigned short*)qlat;     // M*3072 bf16 (= M*1536 f)
    unsigned short* Vt  = (unsigned short*)kvraw;    // M*2048 bf16 (fits kvraw+kvc)
    float* attn = kvb;                               // M*2048 f (kvb dead after packs)

    // 1) q_lat = x @ Wqa^T ; kv_raw = x @ Wkva^T
    gemm_nt<<<dim3(QLORA / TBN, M / TBM), 256, 0, stream>>>(x, Wqa, qlat, M, QLORA, D_);
    gemm_nt<<<dim3(576 / TBN, M / TBM), 256, 0, stream>>>(x, Wkva, kvraw, M, 576, D_);

    // 2) norms + k_pe rope
    rmsnorm_kernel<<<M, 256, 0, stream>>>(qlat, qlw, QLORA);
    kv_post<<<M, 256, 0, stream>>>(kvraw, kvw, fc, kvc, kpe);

    // 3) q = qlat_n @ Wqb^T ; rope q_pe ; kvb = kvc @ Wkvb^T
    gemm_nt<<<dim3(H_ * DQK / TBN, M / TBM), 256, 0, stream>>>(qlat, Wqb, q, M, H_ * DQK, QLORA);
    q_rope<<<M, 256, 0, stream>>>(q, fc);
    gemm_nt<<<dim3(H_ * 256 / TBN, M / TBM), 256, 0, stream>>>(kvc, Wkvb, kvb, M, H_ * 256, KVLORA);

    // 4) pack K/V to bf16 (qlat/kvraw/kvc regions are dead now)
    {
        int total = B_ * H_ * S_ * (DQK / 8);
        pack_k<<<(total + 255) / 256, 256, 0, stream>>>(kvb, kpe, Kbf);
        pack_vt<<<dim3(S_ / 64, B_ * H_), 256, 0, stream>>>(kvb, Vt);
    }

    // 5) MFMA flash attention
    flash_mfma<<<dim3(S_ / 64, H_, B_), 256, 0, stream>>>(q, Kbf, Vt, attn);

    // 6) out = attn @ Wo^T
    gemm_nt<<<dim3(D_ / TBN, M / TBM), 256, 0, stream>>>(attn, Wo, out, M, D_, D_);
}

// Round 5
// 730.392 us; speedup vs baseline: 5.9778x; 3.0538x over previous
//
#include <hip/hip_runtime.h>
#include <math.h>

#define B_ 2
#define S_ 2048
#define D_ 2048
#define H_ 16
#define QLORA 1536
#define KVLORA 512
#define DN 128
#define DR 64
#define DQK 192
#define DV 128
#define EPSF 1e-6f
#define SCALEF 0.07216878364870322f   // 192^-0.5

typedef short short8 __attribute__((ext_vector_type(8)));
typedef float float4v __attribute__((ext_vector_type(4)));

__device__ __forceinline__ unsigned short f2bf(float f) {
    union { float f; unsigned u; } x; x.f = f;
    unsigned r = x.u + 0x7fffu + ((x.u >> 16) & 1u);   // RNE
    return (unsigned short)(r >> 16);
}

// ---------------------------------------------------------------------------
// fp32 -> bf16 elementwise. n must be a multiple of 2048 (all our sizes are).
// ---------------------------------------------------------------------------
__global__ __launch_bounds__(256) void conv_b(const float* __restrict__ X,
                                              unsigned short* __restrict__ Y) {
    const size_t c = (size_t)blockIdx.x * 256 + threadIdx.x;  // 8-elem chunk
    const float* p = X + c * 8;
    float4 a = *(const float4*)(p);
    float4 b = *(const float4*)(p + 4);
    union { short8 v; unsigned short u[8]; } t;
    t.u[0] = f2bf(a.x); t.u[1] = f2bf(a.y); t.u[2] = f2bf(a.z); t.u[3] = f2bf(a.w);
    t.u[4] = f2bf(b.x); t.u[5] = f2bf(b.y); t.u[6] = f2bf(b.z); t.u[7] = f2bf(b.w);
    *(short8*)&Y[c * 8] = t.v;
}

// ---------------------------------------------------------------------------
// bf16 MFMA GEMM:  C[M,N] fp32 = A[M,K] @ W[N,K]^T, A/W bf16 row-major.
// 128x128 tile, BK=64, 256 threads = 4 waves (2x2), each wave 64x64 out.
// ---------------------------------------------------------------------------
#define GBM 128
#define GBN 128
#define GBK 64
#define LDK 72   // padded LDS row stride (bf16 elems): +16B keeps alignment, 2-way banks

__global__ __launch_bounds__(256) void gemm_bf16(const unsigned short* __restrict__ A,
                                                 const unsigned short* __restrict__ W,
                                                 float* __restrict__ C,
                                                 int M, int N, int K) {
    __shared__ unsigned short As[GBM][LDK];   // 18432 B
    __shared__ unsigned short Ws[GBN][LDK];   // 18432 B

    const int tid = threadIdx.x;
    const int w = tid >> 6, lane = tid & 63;
    const int l16 = lane & 15, quad = lane >> 4;
    const int wm = (w >> 1) * 64, wn = (w & 1) * 64;
    const int row0 = blockIdx.y * GBM, col0 = blockIdx.x * GBN;

    const float4v zf = {0.f, 0.f, 0.f, 0.f};
    float4v acc[4][4] = {{zf, zf, zf, zf}, {zf, zf, zf, zf},
                         {zf, zf, zf, zf}, {zf, zf, zf, zf}};

    for (int k0 = 0; k0 < K; k0 += GBK) {
        __syncthreads();
        // stage A tile: 128 rows x 64 cols = 1024 16B-chunks, 4 per thread
#pragma unroll
        for (int i = 0; i < 4; ++i) {
            int c = tid + i * 256;
            int r = c >> 3, col = (c & 7) * 8;
            *(short8*)&As[r][col] = *(const short8*)&A[(size_t)(row0 + r) * K + k0 + col];
        }
#pragma unroll
        for (int i = 0; i < 4; ++i) {
            int c = tid + i * 256;
            int r = c >> 3, col = (c & 7) * 8;
            *(short8*)&Ws[r][col] = *(const short8*)&W[(size_t)(col0 + r) * K + k0 + col];
        }
        __syncthreads();

#pragma unroll
        for (int kk = 0; kk < 2; ++kk) {
            short8 af[4], bf[4];
#pragma unroll
            for (int mi = 0; mi < 4; ++mi)
                af[mi] = *(const short8*)&As[wm + mi * 16 + l16][kk * 32 + quad * 8];
#pragma unroll
            for (int ni = 0; ni < 4; ++ni)
                bf[ni] = *(const short8*)&Ws[wn + ni * 16 + l16][kk * 32 + quad * 8];
#pragma unroll
            for (int mi = 0; mi < 4; ++mi)
#pragma unroll
                for (int ni = 0; ni < 4; ++ni)
                    acc[mi][ni] = __builtin_amdgcn_mfma_f32_16x16x32_bf16(af[mi], bf[ni], acc[mi][ni], 0, 0, 0);
        }
    }

    // epilogue: C/D layout col=l16, row=quad*4+r
#pragma unroll
    for (int mi = 0; mi < 4; ++mi)
#pragma unroll
        for (int ni = 0; ni < 4; ++ni)
#pragma unroll
            for (int r = 0; r < 4; ++r)
                C[(size_t)(row0 + wm + mi * 16 + quad * 4 + r) * N + col0 + wn + ni * 16 + l16] =
                    acc[mi][ni][r];
}

// ---------------------------------------------------------------------------
// RMSNorm rows of length n (fp32 in) -> bf16 out
// ---------------------------------------------------------------------------
__global__ __launch_bounds__(256) void rmsnorm_b(const float* __restrict__ X,
                                                 const float* __restrict__ w,
                                                 unsigned short* __restrict__ Y,
                                                 int n) {
    __shared__ float tmp[4];
    const int row = blockIdx.x;
    const int tid = threadIdx.x;
    const float* x = X + (size_t)row * n;

    float ss = 0.f;
    for (int c = tid; c < n; c += 256) {
        float v = x[c];
        ss = fmaf(v, v, ss);
    }
#pragma unroll
    for (int off = 32; off; off >>= 1) ss += __shfl_xor(ss, off, 64);
    if ((tid & 63) == 0) tmp[tid >> 6] = ss;
    __syncthreads();
    ss = tmp[0] + tmp[1] + tmp[2] + tmp[3];
    float r = rsqrtf(ss / (float)n + EPSF);

    for (int c = tid; c < n; c += 256)
        Y[(size_t)row * n + c] = f2bf(x[c] * r * w[c]);
}

// ---------------------------------------------------------------------------
// kv post-process: row of kvraw (stride ldkv, 576 valid cols).
//   cols 0..511  -> RMSNorm * w -> kvcb bf16 (512-wide)
//   cols 512..575 -> RoPE       -> kpe fp32 (64-wide)
// ---------------------------------------------------------------------------
__global__ __launch_bounds__(256) void kv_post(const float* __restrict__ KV,
                                               const float* __restrict__ w,
                                               const float* __restrict__ fc,
                                               unsigned short* __restrict__ kvcb,
                                               float* __restrict__ kpe,
                                               int ldkv) {
    __shared__ float tmp[4];
    const int row = blockIdx.x;
    const int s = row & (S_ - 1);
    const int tid = threadIdx.x;
    const float* kv = KV + (size_t)row * ldkv;

    float ss = 0.f;
#pragma unroll
    for (int c = tid; c < KVLORA; c += 256) {
        float v = kv[c];
        ss = fmaf(v, v, ss);
    }
#pragma unroll
    for (int off = 32; off; off >>= 1) ss += __shfl_xor(ss, off, 64);
    if ((tid & 63) == 0) tmp[tid >> 6] = ss;
    __syncthreads();
    ss = tmp[0] + tmp[1] + tmp[2] + tmp[3];
    float r = rsqrtf(ss / (float)KVLORA + EPSF);

#pragma unroll
    for (int c = tid; c < KVLORA; c += 256)
        kvcb[(size_t)row * KVLORA + c] = f2bf(kv[c] * r * w[c]);

    if (tid < 32) {
        int i = tid;
        float c0 = fc[(s * 32 + i) * 2 + 0];
        float s0 = fc[(s * 32 + i) * 2 + 1];
        float x0 = kv[KVLORA + 2 * i];
        float x1 = kv[KVLORA + 2 * i + 1];
        kpe[(size_t)row * DR + 2 * i]     = x0 * c0 - x1 * s0;
        kpe[(size_t)row * DR + 2 * i + 1] = x0 * s0 + x1 * c0;
    }
}

// ---------------------------------------------------------------------------
__global__ __launch_bounds__(256) void q_rope(float* __restrict__ Q,
                                              const float* __restrict__ fc) {
    const int row = blockIdx.x;
    const int s = row & (S_ - 1);
    const int tid = threadIdx.x;
#pragma unroll
    for (int idx = tid; idx < H_ * 32; idx += 256) {
        int h = idx >> 5;
        int i = idx & 31;
        float c0 = fc[(s * 32 + i) * 2 + 0];
        float s0 = fc[(s * 32 + i) * 2 + 1];
        float* qp = Q + (size_t)row * (H_ * DQK) + h * DQK + DN + 2 * i;
        float x0 = qp[0];
        float x1 = qp[1];
        qp[0] = x0 * c0 - x1 * s0;
        qp[1] = x0 * s0 + x1 * c0;
    }
}

// ---------------------------------------------------------------------------
// pack_k: Kbf (B,H,S,192) bf16 from kvb (M, H*256) fp32 + kpe (M,64) fp32
// ---------------------------------------------------------------------------
__global__ __launch_bounds__(256) void pack_k(const float* __restrict__ kvb,
                                              const float* __restrict__ kpe,
                                              unsigned short* __restrict__ Kbf) {
    const int c = blockIdx.x * 256 + threadIdx.x;   // chunk of 8 elems
    const int total = B_ * H_ * S_ * (DQK / 8);
    if (c >= total) return;
    const int d8 = c % (DQK / 8);
    const int hs = c / (DQK / 8);
    const int s  = hs % S_;
    const int bh = hs / S_;
    const int b  = bh / H_;
    const int h  = bh % H_;
    const int d  = d8 * 8;
    const int row = b * S_ + s;

    const float* src;
    if (d < DN) src = kvb + (size_t)row * (H_ * 256) + h * 256 + d;
    else        src = kpe + (size_t)row * DR + (d - DN);

    float4 a = *(const float4*)(src);
    float4 bb = *(const float4*)(src + 4);
    union { short8 v; unsigned short u[8]; } t;
    t.u[0] = f2bf(a.x);  t.u[1] = f2bf(a.y);  t.u[2] = f2bf(a.z);  t.u[3] = f2bf(a.w);
    t.u[4] = f2bf(bb.x); t.u[5] = f2bf(bb.y); t.u[6] = f2bf(bb.z); t.u[7] = f2bf(bb.w);
    *(short8*)&Kbf[(size_t)c * 8] = t.v;
}

// ---------------------------------------------------------------------------
// pack_vt: Vt (B,H,128,S) bf16 from kvb (M,H*256) cols h*256+128..+256
// ---------------------------------------------------------------------------
__global__ __launch_bounds__(256) void pack_vt(const float* __restrict__ kvb,
                                               unsigned short* __restrict__ Vt) {
    __shared__ unsigned short T[DV][72];
    const int st = blockIdx.x;            // seq tile (64)
    const int bh = blockIdx.y;            // b*H+h
    const int b = bh >> 4, h = bh & 15;
    const int s0 = st * 64;
    const int tid = threadIdx.x;

    for (int c = tid; c < 64 * 16; c += 256) {
        int sp = c >> 4, ch = c & 15;
        const float* src = kvb + (size_t)(b * S_ + s0 + sp) * (H_ * 256) + h * 256 + DN + ch * 8;
        float4 a = *(const float4*)(src);
        float4 bb = *(const float4*)(src + 4);
        int dv = ch * 8;
        T[dv + 0][sp] = f2bf(a.x);  T[dv + 1][sp] = f2bf(a.y);
        T[dv + 2][sp] = f2bf(a.z);  T[dv + 3][sp] = f2bf(a.w);
        T[dv + 4][sp] = f2bf(bb.x); T[dv + 5][sp] = f2bf(bb.y);
        T[dv + 6][sp] = f2bf(bb.z); T[dv + 7][sp] = f2bf(bb.w);
    }
    __syncthreads();
    for (int c = tid; c < 128 * 8; c += 256) {
        int dv = c >> 3, ch = c & 7;
        *(short8*)&Vt[((size_t)bh * DV + dv) * S_ + s0 + ch * 8] = *(short8*)&T[dv][ch * 8];
    }
}

// ---------------------------------------------------------------------------
// MFMA flash attention (causal), bf16 in, fp32 accumulate, bf16 out.
// ---------------------------------------------------------------------------
#define KROW 200    // 192+8 bf16 pad
#define VROW 72     // 64+8
#define PROW 72

__global__ __launch_bounds__(256) void flash_mfma(const float* __restrict__ Qf,
                                                  const unsigned short* __restrict__ Kbf,
                                                  const unsigned short* __restrict__ Vt,
                                                  unsigned short* __restrict__ Ob) {
    __shared__ unsigned short Ks[64][KROW];     // 25600 B
    __shared__ unsigned short Vs[DV][VROW];     // 18432 B
    __shared__ unsigned short Ps[4][16][PROW];  //  9216 B

    const int q0 = blockIdx.x * 64;
    const int h = blockIdx.y, b = blockIdx.z;
    const int tid = threadIdx.x;
    const int w = tid >> 6, lane = tid & 63;
    const int l16 = lane & 15, quad = lane >> 4;

    const size_t bh = (size_t)b * H_ + h;
    const unsigned short* Kg = Kbf + bh * S_ * DQK;
    const unsigned short* Vg = Vt + bh * DV * S_;

    // Q A-frags: rows q0+16w+l16, d = i*32 + quad*8 .. +8
    short8 a_q[6];
    {
        const float* qrow = Qf + (size_t)(b * S_ + q0 + w * 16 + l16) * (H_ * DQK) + h * DQK;
#pragma unroll
        for (int i = 0; i < 6; ++i) {
            const float* p = qrow + i * 32 + quad * 8;
            float4 a = *(const float4*)(p);
            float4 bb = *(const float4*)(p + 4);
            union { short8 v; unsigned short u[8]; } t;
            t.u[0] = f2bf(a.x);  t.u[1] = f2bf(a.y);  t.u[2] = f2bf(a.z);  t.u[3] = f2bf(a.w);
            t.u[4] = f2bf(bb.x); t.u[5] = f2bf(bb.y); t.u[6] = f2bf(bb.z); t.u[7] = f2bf(bb.w);
            a_q[i] = t.v;
        }
    }

    const float4v zf = {0.f, 0.f, 0.f, 0.f};
    float4v o_acc[8] = {zf, zf, zf, zf, zf, zf, zf, zf};
    float m_r[4] = {-1e30f, -1e30f, -1e30f, -1e30f};
    float l_r[4] = {0.f, 0.f, 0.f, 0.f};

    const int ntiles = q0 / 64 + 1;
    for (int kt = 0; kt < ntiles; ++kt) {
        const int kbase = kt * 64;
        __syncthreads();
        // stage K tile: 64 rows x 192 bf16 = 24 short8-chunks per row
        for (int c = tid; c < 64 * 24; c += 256) {
            int r = c / 24, cc = c % 24;
            *(short8*)&Ks[r][cc * 8] =
                *(const short8*)&Kg[(size_t)(kbase + r) * DQK + cc * 8];
        }
        // stage V tile: 128 dv-rows x 64 keys = 8 short8-chunks per row
        for (int c = tid; c < 128 * 8; c += 256) {
            int r = c >> 3, cc = c & 7;
            *(short8*)&Vs[r][cc * 8] =
                *(const short8*)&Vg[(size_t)r * S_ + kbase + cc * 8];
        }
        __syncthreads();

        // QK^T
        float4v sc[4] = {zf, zf, zf, zf};
#pragma unroll
        for (int kg = 0; kg < 4; ++kg) {
#pragma unroll
            for (int i = 0; i < 6; ++i) {
                short8 bk = *(const short8*)&Ks[kg * 16 + l16][i * 32 + quad * 8];
                sc[kg] = __builtin_amdgcn_mfma_f32_16x16x32_bf16(a_q[i], bk, sc[kg], 0, 0, 0);
            }
        }

        float scv[4][4];
#pragma unroll
        for (int kg = 0; kg < 4; ++kg)
#pragma unroll
            for (int r = 0; r < 4; ++r)
                scv[kg][r] = sc[kg][r] * SCALEF;

        if (kt == ntiles - 1) {
#pragma unroll
            for (int kg = 0; kg < 4; ++kg) {
                int key = kbase + kg * 16 + l16;
#pragma unroll
                for (int r = 0; r < 4; ++r) {
                    int row = q0 + w * 16 + quad * 4 + r;
                    if (key > row) scv[kg][r] = -1e30f;
                }
            }
        }

        float mnew[4];
#pragma unroll
        for (int r = 0; r < 4; ++r) {
            float t = fmaxf(fmaxf(scv[0][r], scv[1][r]), fmaxf(scv[2][r], scv[3][r]));
            t = fmaxf(t, __shfl_xor(t, 1));
            t = fmaxf(t, __shfl_xor(t, 2));
            t = fmaxf(t, __shfl_xor(t, 4));
            t = fmaxf(t, __shfl_xor(t, 8));
            mnew[r] = fmaxf(m_r[r], t);
            float a = __expf(m_r[r] - mnew[r]);
            m_r[r] = mnew[r];
            l_r[r] *= a;
#pragma unroll
            for (int dvt = 0; dvt < 8; ++dvt) o_acc[dvt][r] *= a;
        }

        float psum[4] = {0.f, 0.f, 0.f, 0.f};
#pragma unroll
        for (int kg = 0; kg < 4; ++kg)
#pragma unroll
            for (int r = 0; r < 4; ++r) {
                float p = __expf(scv[kg][r] - mnew[r]);
                psum[r] += p;
                Ps[w][quad * 4 + r][kg * 16 + l16] = f2bf(p);
            }
#pragma unroll
        for (int r = 0; r < 4; ++r) {
            float t = psum[r];
            t += __shfl_xor(t, 1);
            t += __shfl_xor(t, 2);
            t += __shfl_xor(t, 4);
            t += __shfl_xor(t, 8);
            l_r[r] += t;
        }

        __syncthreads();   // P writes visible before A-frag reads

        // PV
#pragma unroll
        for (int kc = 0; kc < 2; ++kc) {
            short8 pa = *(const short8*)&Ps[w][l16][kc * 32 + quad * 8];
#pragma unroll
            for (int dvt = 0; dvt < 8; ++dvt) {
                short8 vb = *(const short8*)&Vs[dvt * 16 + l16][kc * 32 + quad * 8];
                o_acc[dvt] = __builtin_amdgcn_mfma_f32_16x16x32_bf16(pa, vb, o_acc[dvt], 0, 0, 0);
            }
        }
    }

    // epilogue -> bf16
#pragma unroll
    for (int r = 0; r < 4; ++r) {
        float inv = 1.f / l_r[r];
        int row = q0 + w * 16 + quad * 4 + r;
        unsigned short* op = Ob + (size_t)(b * S_ + row) * (H_ * DV) + h * DV;
#pragma unroll
        for (int dvt = 0; dvt < 8; ++dvt)
            op[dvt * 16 + l16] = f2bf(o_acc[dvt][r] * inv);
    }
}

// ---------------------------------------------------------------------------
extern "C" void kernel_launch(void* const* d_in, const int* in_sizes, int n_in,
                              void* d_out, int out_size, void* d_ws, size_t ws_size,
                              hipStream_t stream) {
    const float* x    = (const float*)d_in[0];
    const float* fc   = (const float*)d_in[1];
    const float* Wqa  = (const float*)d_in[2];
    const float* qlw  = (const float*)d_in[3];
    const float* Wqb  = (const float*)d_in[4];
    const float* Wkva = (const float*)d_in[5];
    const float* kvw  = (const float*)d_in[6];
    const float* Wkvb = (const float*)d_in[7];
    const float* Wo   = (const float*)d_in[8];
    float* out = (float*)d_out;

    const int M = B_ * S_;                 // 4096
    char* wsb = (char*)d_ws;

    // R1: q fp32 (M*3072*4 = 50331648 B), lives steps 6-10
    float* q = (float*)wsb;
    // R2 (size 67108864 = kvb): early-phase residents, all dead before kvb write
    char* R2 = wsb + 50331648;
    float*          qlat  = (float*)R2;                          // 25165824 B
    unsigned short* xb    = (unsigned short*)(R2 + 25165824);    // 16777216 B
    unsigned short* Wqab  = (unsigned short*)(R2 + 41943040);    //  6291456 B
    unsigned short* Wkvab = (unsigned short*)(R2 + 48234496);    //  2621440 B (640 rows, 576 written)
    unsigned short* Wqbb  = (unsigned short*)(R2 + 50855936);    //  9437184 B -> 60293120
    float*          kvb   = (float*)R2;                          // step 8: 67108864 B
    unsigned short* attnb = (unsigned short*)R2;                 // step 10: 16777216 B
    // R3 (size 25165824 = Kbf)
    char* R3 = R2 + 67108864;
    float*          kvraw = (float*)R3;                          // 10485760 B (M*640*4)
    unsigned short* qlatb = (unsigned short*)(R3 + 10485760);    // 12582912 B -> 23068672
    unsigned short* Kbf   = (unsigned short*)R3;                 // step 9
    unsigned short* Wob   = (unsigned short*)R3;                 // after flash: 8388608 B
    // R4 (size 16777216 = Vt)
    char* R4 = R3 + 25165824;
    float*          kpe   = (float*)R4;                          //  1048576 B
    unsigned short* kvcb  = (unsigned short*)(R4 + 1048576);     //  4194304 B
    unsigned short* Wkvbb = (unsigned short*)(R4 + 5242880);     //  4194304 B -> 9437184
    unsigned short* Vt    = (unsigned short*)R4;                 // step 9 (after pack_k!)
    // total ws = 159383552 B

    // 0) bf16 conversions (x + early weights)
    conv_b<<<(M * D_) / 2048, 256, 0, stream>>>(x, xb);
    conv_b<<<(QLORA * D_) / 2048, 256, 0, stream>>>(Wqa, Wqab);
    conv_b<<<(576 * D_) / 2048, 256, 0, stream>>>(Wkva, Wkvab);
    conv_b<<<(H_ * DQK * QLORA) / 2048, 256, 0, stream>>>(Wqb, Wqbb);
    conv_b<<<(H_ * 256 * KVLORA) / 2048, 256, 0, stream>>>(Wkvb, Wkvbb);

    // 1) qlat = xb @ Wqab^T ; kvraw = xb @ Wkvab^T (N padded to 640)
    gemm_bf16<<<dim3(QLORA / GBN, M / GBM), 256, 0, stream>>>(xb, Wqab, qlat, M, QLORA, D_);
    gemm_bf16<<<dim3(640 / GBN, M / GBM), 256, 0, stream>>>(xb, Wkvab, kvraw, M, 640, D_);

    // 2) norms (emit bf16) + k_pe rope
    rmsnorm_b<<<M, 256, 0, stream>>>(qlat, qlw, qlatb, QLORA);
    kv_post<<<M, 256, 0, stream>>>(kvraw, kvw, fc, kvcb, kpe, 640);

    // 3) q = qlatb @ Wqbb^T ; rope q_pe ; kvb = kvcb @ Wkvbb^T
    gemm_bf16<<<dim3(H_ * DQK / GBN, M / GBM), 256, 0, stream>>>(qlatb, Wqbb, q, M, H_ * DQK, QLORA);
    q_rope<<<M, 256, 0, stream>>>(q, fc);
    gemm_bf16<<<dim3(H_ * 256 / GBN, M / GBM), 256, 0, stream>>>(kvcb, Wkvbb, kvb, M, H_ * 256, KVLORA);

    // 4) pack K then V (pack_k reads kpe which Vt overwrites -> strict order)
    {
        int total = B_ * H_ * S_ * (DQK / 8);
        pack_k<<<(total + 255) / 256, 256, 0, stream>>>(kvb, kpe, Kbf);
        pack_vt<<<dim3(S_ / 64, B_ * H_), 256, 0, stream>>>(kvb, Vt);
    }

    // 5) MFMA flash attention -> bf16 attn
    flash_mfma<<<dim3(S_ / 64, H_, B_), 256, 0, stream>>>(q, Kbf, Vt, attnb);

    // 6) convert Wo (into dead Kbf region) and final GEMM
    conv_b<<<(D_ * H_ * DV) / 2048, 256, 0, stream>>>(Wo, Wob);
    gemm_bf16<<<dim3(D_ / GBN, M / GBM), 256, 0, stream>>>(attnb, Wob, out, M, D_, D_);
}

// Round 6
// 533.125 us; speedup vs baseline: 8.1896x; 1.3700x over previous
//
#include <hip/hip_runtime.h>
#include <math.h>

#define B_ 2
#define S_ 2048
#define D_ 2048
#define H_ 16
#define QLORA 1536
#define KVLORA 512
#define DN 128
#define DR 64
#define DQK 192
#define DV 128
#define EPSF 1e-6f
#define SCALEF 0.07216878364870322f   // 192^-0.5

typedef short short8 __attribute__((ext_vector_type(8)));
typedef float float4v __attribute__((ext_vector_type(4)));

__device__ __forceinline__ unsigned short f2bf(float f) {
    union { float f; unsigned u; } x; x.f = f;
    unsigned r = x.u + 0x7fffu + ((x.u >> 16) & 1u);   // RNE
    return (unsigned short)(r >> 16);
}

// ---------------------------------------------------------------------------
// fp32 -> bf16 elementwise. n must be a multiple of 2048.
// ---------------------------------------------------------------------------
__global__ __launch_bounds__(256) void conv_b(const float* __restrict__ X,
                                              unsigned short* __restrict__ Y) {
    const size_t c = (size_t)blockIdx.x * 256 + threadIdx.x;  // 8-elem chunk
    const float* p = X + c * 8;
    float4 a = *(const float4*)(p);
    float4 b = *(const float4*)(p + 4);
    union { short8 v; unsigned short u[8]; } t;
    t.u[0] = f2bf(a.x); t.u[1] = f2bf(a.y); t.u[2] = f2bf(a.z); t.u[3] = f2bf(a.w);
    t.u[4] = f2bf(b.x); t.u[5] = f2bf(b.y); t.u[6] = f2bf(b.z); t.u[7] = f2bf(b.w);
    *(short8*)&Y[c * 8] = t.v;
}

// ---------------------------------------------------------------------------
// bf16 MFMA GEMM:  C[M,N] fp32 = A[M,K] @ W[N,K]^T, A/W bf16 row-major.
// 128x128 tile, BK=64, 256 threads = 4 waves (2x2), each wave 64x64 out.
// ---------------------------------------------------------------------------
#define GBM 128
#define GBN 128
#define GBK 64
#define LDK 72   // padded LDS row stride (bf16 elems)

__global__ __launch_bounds__(256) void gemm_bf16(const unsigned short* __restrict__ A,
                                                 const unsigned short* __restrict__ W,
                                                 float* __restrict__ C,
                                                 int M, int N, int K) {
    __shared__ unsigned short As[GBM][LDK];   // 18432 B
    __shared__ unsigned short Ws[GBN][LDK];   // 18432 B

    const int tid = threadIdx.x;
    const int w = tid >> 6, lane = tid & 63;
    const int l16 = lane & 15, quad = lane >> 4;
    const int wm = (w >> 1) * 64, wn = (w & 1) * 64;
    const int row0 = blockIdx.y * GBM, col0 = blockIdx.x * GBN;

    const float4v zf = {0.f, 0.f, 0.f, 0.f};
    float4v acc[4][4] = {{zf, zf, zf, zf}, {zf, zf, zf, zf},
                         {zf, zf, zf, zf}, {zf, zf, zf, zf}};

    for (int k0 = 0; k0 < K; k0 += GBK) {
        __syncthreads();
#pragma unroll
        for (int i = 0; i < 4; ++i) {
            int c = tid + i * 256;
            int r = c >> 3, col = (c & 7) * 8;
            *(short8*)&As[r][col] = *(const short8*)&A[(size_t)(row0 + r) * K + k0 + col];
        }
#pragma unroll
        for (int i = 0; i < 4; ++i) {
            int c = tid + i * 256;
            int r = c >> 3, col = (c & 7) * 8;
            *(short8*)&Ws[r][col] = *(const short8*)&W[(size_t)(col0 + r) * K + k0 + col];
        }
        __syncthreads();

#pragma unroll
        for (int kk = 0; kk < 2; ++kk) {
            short8 af[4], bf[4];
#pragma unroll
            for (int mi = 0; mi < 4; ++mi)
                af[mi] = *(const short8*)&As[wm + mi * 16 + l16][kk * 32 + quad * 8];
#pragma unroll
            for (int ni = 0; ni < 4; ++ni)
                bf[ni] = *(const short8*)&Ws[wn + ni * 16 + l16][kk * 32 + quad * 8];
#pragma unroll
            for (int mi = 0; mi < 4; ++mi)
#pragma unroll
                for (int ni = 0; ni < 4; ++ni)
                    acc[mi][ni] = __builtin_amdgcn_mfma_f32_16x16x32_bf16(af[mi], bf[ni], acc[mi][ni], 0, 0, 0);
        }
    }

#pragma unroll
    for (int mi = 0; mi < 4; ++mi)
#pragma unroll
        for (int ni = 0; ni < 4; ++ni)
#pragma unroll
            for (int r = 0; r < 4; ++r)
                C[(size_t)(row0 + wm + mi * 16 + quad * 4 + r) * N + col0 + wn + ni * 16 + l16] =
                    acc[mi][ni][r];
}

// ---------------------------------------------------------------------------
__global__ __launch_bounds__(256) void rmsnorm_b(const float* __restrict__ X,
                                                 const float* __restrict__ w,
                                                 unsigned short* __restrict__ Y,
                                                 int n) {
    __shared__ float tmp[4];
    const int row = blockIdx.x;
    const int tid = threadIdx.x;
    const float* x = X + (size_t)row * n;

    float ss = 0.f;
    for (int c = tid; c < n; c += 256) {
        float v = x[c];
        ss = fmaf(v, v, ss);
    }
#pragma unroll
    for (int off = 32; off; off >>= 1) ss += __shfl_xor(ss, off, 64);
    if ((tid & 63) == 0) tmp[tid >> 6] = ss;
    __syncthreads();
    ss = tmp[0] + tmp[1] + tmp[2] + tmp[3];
    float r = rsqrtf(ss / (float)n + EPSF);

    for (int c = tid; c < n; c += 256)
        Y[(size_t)row * n + c] = f2bf(x[c] * r * w[c]);
}

// ---------------------------------------------------------------------------
__global__ __launch_bounds__(256) void kv_post(const float* __restrict__ KV,
                                               const float* __restrict__ w,
                                               const float* __restrict__ fc,
                                               unsigned short* __restrict__ kvcb,
                                               float* __restrict__ kpe,
                                               int ldkv) {
    __shared__ float tmp[4];
    const int row = blockIdx.x;
    const int s = row & (S_ - 1);
    const int tid = threadIdx.x;
    const float* kv = KV + (size_t)row * ldkv;

    float ss = 0.f;
#pragma unroll
    for (int c = tid; c < KVLORA; c += 256) {
        float v = kv[c];
        ss = fmaf(v, v, ss);
    }
#pragma unroll
    for (int off = 32; off; off >>= 1) ss += __shfl_xor(ss, off, 64);
    if ((tid & 63) == 0) tmp[tid >> 6] = ss;
    __syncthreads();
    ss = tmp[0] + tmp[1] + tmp[2] + tmp[3];
    float r = rsqrtf(ss / (float)KVLORA + EPSF);

#pragma unroll
    for (int c = tid; c < KVLORA; c += 256)
        kvcb[(size_t)row * KVLORA + c] = f2bf(kv[c] * r * w[c]);

    if (tid < 32) {
        int i = tid;
        float c0 = fc[(s * 32 + i) * 2 + 0];
        float s0 = fc[(s * 32 + i) * 2 + 1];
        float x0 = kv[KVLORA + 2 * i];
        float x1 = kv[KVLORA + 2 * i + 1];
        kpe[(size_t)row * DR + 2 * i]     = x0 * c0 - x1 * s0;
        kpe[(size_t)row * DR + 2 * i + 1] = x0 * s0 + x1 * c0;
    }
}

// ---------------------------------------------------------------------------
__global__ __launch_bounds__(256) void q_rope(float* __restrict__ Q,
                                              const float* __restrict__ fc) {
    const int row = blockIdx.x;
    const int s = row & (S_ - 1);
    const int tid = threadIdx.x;
#pragma unroll
    for (int idx = tid; idx < H_ * 32; idx += 256) {
        int h = idx >> 5;
        int i = idx & 31;
        float c0 = fc[(s * 32 + i) * 2 + 0];
        float s0 = fc[(s * 32 + i) * 2 + 1];
        float* qp = Q + (size_t)row * (H_ * DQK) + h * DQK + DN + 2 * i;
        float x0 = qp[0];
        float x1 = qp[1];
        qp[0] = x0 * c0 - x1 * s0;
        qp[1] = x0 * s0 + x1 * c0;
    }
}

// ---------------------------------------------------------------------------
__global__ __launch_bounds__(256) void pack_k(const float* __restrict__ kvb,
                                              const float* __restrict__ kpe,
                                              unsigned short* __restrict__ Kbf) {
    const int c = blockIdx.x * 256 + threadIdx.x;   // chunk of 8 elems
    const int total = B_ * H_ * S_ * (DQK / 8);
    if (c >= total) return;
    const int d8 = c % (DQK / 8);
    const int hs = c / (DQK / 8);
    const int s  = hs % S_;
    const int bh = hs / S_;
    const int b  = bh / H_;
    const int h  = bh % H_;
    const int d  = d8 * 8;
    const int row = b * S_ + s;

    const float* src;
    if (d < DN) src = kvb + (size_t)row * (H_ * 256) + h * 256 + d;
    else        src = kpe + (size_t)row * DR + (d - DN);

    float4 a = *(const float4*)(src);
    float4 bb = *(const float4*)(src + 4);
    union { short8 v; unsigned short u[8]; } t;
    t.u[0] = f2bf(a.x);  t.u[1] = f2bf(a.y);  t.u[2] = f2bf(a.z);  t.u[3] = f2bf(a.w);
    t.u[4] = f2bf(bb.x); t.u[5] = f2bf(bb.y); t.u[6] = f2bf(bb.z); t.u[7] = f2bf(bb.w);
    *(short8*)&Kbf[(size_t)c * 8] = t.v;
}

// ---------------------------------------------------------------------------
__global__ __launch_bounds__(256) void pack_vt(const float* __restrict__ kvb,
                                               unsigned short* __restrict__ Vt) {
    __shared__ unsigned short T[DV][72];
    const int st = blockIdx.x;            // seq tile (64)
    const int bh = blockIdx.y;            // b*H+h
    const int b = bh >> 4, h = bh & 15;
    const int s0 = st * 64;
    const int tid = threadIdx.x;

    for (int c = tid; c < 64 * 16; c += 256) {
        int sp = c >> 4, ch = c & 15;
        const float* src = kvb + (size_t)(b * S_ + s0 + sp) * (H_ * 256) + h * 256 + DN + ch * 8;
        float4 a = *(const float4*)(src);
        float4 bb = *(const float4*)(src + 4);
        int dv = ch * 8;
        T[dv + 0][sp] = f2bf(a.x);  T[dv + 1][sp] = f2bf(a.y);
        T[dv + 2][sp] = f2bf(a.z);  T[dv + 3][sp] = f2bf(a.w);
        T[dv + 4][sp] = f2bf(bb.x); T[dv + 5][sp] = f2bf(bb.y);
        T[dv + 6][sp] = f2bf(bb.z); T[dv + 7][sp] = f2bf(bb.w);
    }
    __syncthreads();
    for (int c = tid; c < 128 * 8; c += 256) {
        int dv = c >> 3, ch = c & 7;
        *(short8*)&Vt[((size_t)bh * DV + dv) * S_ + s0 + ch * 8] = *(short8*)&T[dv][ch * 8];
    }
}

// ---------------------------------------------------------------------------
// MFMA flash attention (causal), bf16 in, fp32 accumulate, bf16 out.
// Work-balanced: block bx handles q-tiles {bx, 31-bx} sequentially -> every
// block does exactly 34 K-tile steps. Register double-buffer prefetch of the
// next K/V tile overlaps HBM latency with compute.
// ---------------------------------------------------------------------------
#define KROW 200    // 192+8 bf16 pad
#define VROW 72     // 64+8
#define PROW 72
#define NQT 32      // 64-row q-tiles per (b,h)

__global__ __launch_bounds__(256, 2) void flash_mfma(const float* __restrict__ Qf,
                                                     const unsigned short* __restrict__ Kbf,
                                                     const unsigned short* __restrict__ Vt,
                                                     unsigned short* __restrict__ Ob) {
    __shared__ unsigned short Ks[64][KROW];     // 25600 B
    __shared__ unsigned short Vs[DV][VROW];     // 18432 B
    __shared__ unsigned short Ps[4][16][PROW];  //  9216 B

    const int bx = blockIdx.x;                  // 0..15 pair index
    const int h = blockIdx.y, b = blockIdx.z;
    const int tid = threadIdx.x;
    const int w = tid >> 6, lane = tid & 63;
    const int l16 = lane & 15, quad = lane >> 4;

    const size_t bh = (size_t)b * H_ + h;
    const unsigned short* Kg = Kbf + bh * S_ * DQK;
    const unsigned short* Vg = Vt + bh * DV * S_;

    // staging decomposition (per thread, reused every tile)
    const int krA = (tid * 6) / 24, kcA0 = (tid * 6) % 24;  // not used; keep simple below

    for (int half = 0; half < 2; ++half) {
        const int qt = half ? (NQT - 1 - bx) : bx;
        const int q0 = qt * 64;
        const int ntiles = qt + 1;

        // Q A-frags: rows q0+16w+l16, d = i*32 + quad*8
        short8 a_q[6];
        {
            const float* qrow = Qf + (size_t)(b * S_ + q0 + w * 16 + l16) * (H_ * DQK) + h * DQK;
#pragma unroll
            for (int i = 0; i < 6; ++i) {
                const float* p = qrow + i * 32 + quad * 8;
                float4 a = *(const float4*)(p);
                float4 bb = *(const float4*)(p + 4);
                union { short8 v; unsigned short u[8]; } t;
                t.u[0] = f2bf(a.x);  t.u[1] = f2bf(a.y);  t.u[2] = f2bf(a.z);  t.u[3] = f2bf(a.w);
                t.u[4] = f2bf(bb.x); t.u[5] = f2bf(bb.y); t.u[6] = f2bf(bb.z); t.u[7] = f2bf(bb.w);
                a_q[i] = t.v;
            }
        }

        const float4v zf = {0.f, 0.f, 0.f, 0.f};
        float4v o_acc[8] = {zf, zf, zf, zf, zf, zf, zf, zf};
        float m_r[4] = {-1e30f, -1e30f, -1e30f, -1e30f};
        float l_r[4] = {0.f, 0.f, 0.f, 0.f};

        // preload tile 0 into registers
        short8 ldK[6], ldV[4];
#pragma unroll
        for (int i = 0; i < 6; ++i) {
            int c = tid + i * 256;
            int r = c / 24, cc = c % 24;
            ldK[i] = *(const short8*)&Kg[(size_t)r * DQK + cc * 8];
        }
#pragma unroll
        for (int i = 0; i < 4; ++i) {
            int c = tid + i * 256;
            int r = c >> 3, cc = c & 7;
            ldV[i] = *(const short8*)&Vg[(size_t)r * S_ + cc * 8];
        }

        for (int kt = 0; kt < ntiles; ++kt) {
            const int kbase = kt * 64;
            __syncthreads();   // previous compute done; LDS free
            // commit prefetched regs to LDS
#pragma unroll
            for (int i = 0; i < 6; ++i) {
                int c = tid + i * 256;
                int r = c / 24, cc = c % 24;
                *(short8*)&Ks[r][cc * 8] = ldK[i];
            }
#pragma unroll
            for (int i = 0; i < 4; ++i) {
                int c = tid + i * 256;
                int r = c >> 3, cc = c & 7;
                *(short8*)&Vs[r][cc * 8] = ldV[i];
            }
            // prefetch next tile while computing this one
            if (kt + 1 < ntiles) {
                const int kb2 = kbase + 64;
#pragma unroll
                for (int i = 0; i < 6; ++i) {
                    int c = tid + i * 256;
                    int r = c / 24, cc = c % 24;
                    ldK[i] = *(const short8*)&Kg[(size_t)(kb2 + r) * DQK + cc * 8];
                }
#pragma unroll
                for (int i = 0; i < 4; ++i) {
                    int c = tid + i * 256;
                    int r = c >> 3, cc = c & 7;
                    ldV[i] = *(const short8*)&Vg[(size_t)r * S_ + kb2 + cc * 8];
                }
            }
            __syncthreads();   // LDS tile ready

            // QK^T
            float4v sc[4] = {zf, zf, zf, zf};
#pragma unroll
            for (int kg = 0; kg < 4; ++kg) {
#pragma unroll
                for (int i = 0; i < 6; ++i) {
                    short8 bk = *(const short8*)&Ks[kg * 16 + l16][i * 32 + quad * 8];
                    sc[kg] = __builtin_amdgcn_mfma_f32_16x16x32_bf16(a_q[i], bk, sc[kg], 0, 0, 0);
                }
            }

            float scv[4][4];
#pragma unroll
            for (int kg = 0; kg < 4; ++kg)
#pragma unroll
                for (int r = 0; r < 4; ++r)
                    scv[kg][r] = sc[kg][r] * SCALEF;

            if (kt == ntiles - 1) {
#pragma unroll
                for (int kg = 0; kg < 4; ++kg) {
                    int key = kbase + kg * 16 + l16;
#pragma unroll
                    for (int r = 0; r < 4; ++r) {
                        int row = q0 + w * 16 + quad * 4 + r;
                        if (key > row) scv[kg][r] = -1e30f;
                    }
                }
            }

            float mnew[4];
#pragma unroll
            for (int r = 0; r < 4; ++r) {
                float t = fmaxf(fmaxf(scv[0][r], scv[1][r]), fmaxf(scv[2][r], scv[3][r]));
                t = fmaxf(t, __shfl_xor(t, 1));
                t = fmaxf(t, __shfl_xor(t, 2));
                t = fmaxf(t, __shfl_xor(t, 4));
                t = fmaxf(t, __shfl_xor(t, 8));
                mnew[r] = fmaxf(m_r[r], t);
                float a = __expf(m_r[r] - mnew[r]);
                m_r[r] = mnew[r];
                l_r[r] *= a;
#pragma unroll
                for (int dvt = 0; dvt < 8; ++dvt) o_acc[dvt][r] *= a;
            }

            float psum[4] = {0.f, 0.f, 0.f, 0.f};
#pragma unroll
            for (int kg = 0; kg < 4; ++kg)
#pragma unroll
                for (int r = 0; r < 4; ++r) {
                    float p = __expf(scv[kg][r] - mnew[r]);
                    psum[r] += p;
                    Ps[w][quad * 4 + r][kg * 16 + l16] = f2bf(p);
                }
#pragma unroll
            for (int r = 0; r < 4; ++r) {
                float t = psum[r];
                t += __shfl_xor(t, 1);
                t += __shfl_xor(t, 2);
                t += __shfl_xor(t, 4);
                t += __shfl_xor(t, 8);
                l_r[r] += t;
            }

            __syncthreads();   // P writes visible before A-frag reads

            // PV
#pragma unroll
            for (int kc = 0; kc < 2; ++kc) {
                short8 pa = *(const short8*)&Ps[w][l16][kc * 32 + quad * 8];
#pragma unroll
                for (int dvt = 0; dvt < 8; ++dvt) {
                    short8 vb = *(const short8*)&Vs[dvt * 16 + l16][kc * 32 + quad * 8];
                    o_acc[dvt] = __builtin_amdgcn_mfma_f32_16x16x32_bf16(pa, vb, o_acc[dvt], 0, 0, 0);
                }
            }
        }

        // epilogue -> bf16
#pragma unroll
        for (int r = 0; r < 4; ++r) {
            float inv = 1.f / l_r[r];
            int row = q0 + w * 16 + quad * 4 + r;
            unsigned short* op = Ob + (size_t)(b * S_ + row) * (H_ * DV) + h * DV;
#pragma unroll
            for (int dvt = 0; dvt < 8; ++dvt)
                op[dvt * 16 + l16] = f2bf(o_acc[dvt][r] * inv);
        }
    }
}

// ---------------------------------------------------------------------------
extern "C" void kernel_launch(void* const* d_in, const int* in_sizes, int n_in,
                              void* d_out, int out_size, void* d_ws, size_t ws_size,
                              hipStream_t stream) {
    const float* x    = (const float*)d_in[0];
    const float* fc   = (const float*)d_in[1];
    const float* Wqa  = (const float*)d_in[2];
    const float* qlw  = (const float*)d_in[3];
    const float* Wqb  = (const float*)d_in[4];
    const float* Wkva = (const float*)d_in[5];
    const float* kvw  = (const float*)d_in[6];
    const float* Wkvb = (const float*)d_in[7];
    const float* Wo   = (const float*)d_in[8];
    float* out = (float*)d_out;

    const int M = B_ * S_;                 // 4096
    char* wsb = (char*)d_ws;

    // R1: q fp32 (M*3072*4 = 50331648 B)
    float* q = (float*)wsb;
    // R2 (67108864 B): early-phase residents, dead before kvb write
    char* R2 = wsb + 50331648;
    float*          qlat  = (float*)R2;                          // 25165824 B
    unsigned short* xb    = (unsigned short*)(R2 + 25165824);    // 16777216 B
    unsigned short* Wqab  = (unsigned short*)(R2 + 41943040);    //  6291456 B
    unsigned short* Wkvab = (unsigned short*)(R2 + 48234496);    //  2621440 B
    unsigned short* Wqbb  = (unsigned short*)(R2 + 50855936);    //  9437184 B
    float*          kvb   = (float*)R2;                          // step 8
    unsigned short* attnb = (unsigned short*)R2;                 // step 10
    // R3 (25165824 B)
    char* R3 = R2 + 67108864;
    float*          kvraw = (float*)R3;                          // 10485760 B
    unsigned short* qlatb = (unsigned short*)(R3 + 10485760);    // 12582912 B
    unsigned short* Kbf   = (unsigned short*)R3;                 // step 9
    unsigned short* Wob   = (unsigned short*)R3;                 // after flash
    // R4 (16777216 B)
    char* R4 = R3 + 25165824;
    float*          kpe   = (float*)R4;                          //  1048576 B
    unsigned short* kvcb  = (unsigned short*)(R4 + 1048576);     //  4194304 B
    unsigned short* Wkvbb = (unsigned short*)(R4 + 5242880);     //  4194304 B
    unsigned short* Vt    = (unsigned short*)R4;                 // step 9 (after pack_k!)

    // 0) bf16 conversions
    conv_b<<<(M * D_) / 2048, 256, 0, stream>>>(x, xb);
    conv_b<<<(QLORA * D_) / 2048, 256, 0, stream>>>(Wqa, Wqab);
    conv_b<<<(576 * D_) / 2048, 256, 0, stream>>>(Wkva, Wkvab);
    conv_b<<<(H_ * DQK * QLORA) / 2048, 256, 0, stream>>>(Wqb, Wqbb);
    conv_b<<<(H_ * 256 * KVLORA) / 2048, 256, 0, stream>>>(Wkvb, Wkvbb);

    // 1) qlat = xb @ Wqab^T ; kvraw = xb @ Wkvab^T (N padded to 640)
    gemm_bf16<<<dim3(QLORA / GBN, M / GBM), 256, 0, stream>>>(xb, Wqab, qlat, M, QLORA, D_);
    gemm_bf16<<<dim3(640 / GBN, M / GBM), 256, 0, stream>>>(xb, Wkvab, kvraw, M, 640, D_);

    // 2) norms (emit bf16) + k_pe rope
    rmsnorm_b<<<M, 256, 0, stream>>>(qlat, qlw, qlatb, QLORA);
    kv_post<<<M, 256, 0, stream>>>(kvraw, kvw, fc, kvcb, kpe, 640);

    // 3) q = qlatb @ Wqbb^T ; rope q_pe ; kvb = kvcb @ Wkvbb^T
    gemm_bf16<<<dim3(H_ * DQK / GBN, M / GBM), 256, 0, stream>>>(qlatb, Wqbb, q, M, H_ * DQK, QLORA);
    q_rope<<<M, 256, 0, stream>>>(q, fc);
    gemm_bf16<<<dim3(H_ * 256 / GBN, M / GBM), 256, 0, stream>>>(kvcb, Wkvbb, kvb, M, H_ * 256, KVLORA);

    // 4) pack K then V (pack_k reads kpe which Vt overwrites -> strict order)
    {
        int total = B_ * H_ * S_ * (DQK / 8);
        pack_k<<<(total + 255) / 256, 256, 0, stream>>>(kvb, kpe, Kbf);
        pack_vt<<<dim3(S_ / 64, B_ * H_), 256, 0, stream>>>(kvb, Vt);
    }

    // 5) MFMA flash attention (work-balanced pairs) -> bf16 attn
    flash_mfma<<<dim3(NQT / 2, H_, B_), 256, 0, stream>>>(q, Kbf, Vt, attnb);

    // 6) convert Wo (into dead Kbf region) and final GEMM
    conv_b<<<(D_ * H_ * DV) / 2048, 256, 0, stream>>>(Wo, Wob);
    gemm_bf16<<<dim3(D_ / GBN, M / GBM), 256, 0, stream>>>(attnb, Wob, out, M, D_, D_);
}

// Round 7
// 527.285 us; speedup vs baseline: 8.2803x; 1.0111x over previous
//
#include <hip/hip_runtime.h>
#include <math.h>

#define B_ 2
#define S_ 2048
#define D_ 2048
#define H_ 16
#define QLORA 1536
#define KVLORA 512
#define DN 128
#define DR 64
#define DQK 192
#define DV 128
#define EPSF 1e-6f
#define SCALEF 0.07216878364870322f   // 192^-0.5

typedef short short8 __attribute__((ext_vector_type(8)));
typedef float float4v __attribute__((ext_vector_type(4)));

__device__ __forceinline__ unsigned short f2bf(float f) {
    union { float f; unsigned u; } x; x.f = f;
    unsigned r = x.u + 0x7fffu + ((x.u >> 16) & 1u);   // RNE
    return (unsigned short)(r >> 16);
}

// async global->LDS, 16B per lane; LDS dest = wave-uniform base + lane*16
#define GLD16(src, dst)                                                        \
    __builtin_amdgcn_global_load_lds(                                          \
        (const __attribute__((address_space(1))) void*)(src),                  \
        (__attribute__((address_space(3))) void*)(dst), 16, 0, 0)

// ---------------------------------------------------------------------------
// fp32 -> bf16 elementwise. n must be a multiple of 2048.
// ---------------------------------------------------------------------------
__global__ __launch_bounds__(256) void conv_b(const float* __restrict__ X,
                                              unsigned short* __restrict__ Y) {
    const size_t c = (size_t)blockIdx.x * 256 + threadIdx.x;  // 8-elem chunk
    const float* p = X + c * 8;
    float4 a = *(const float4*)(p);
    float4 b = *(const float4*)(p + 4);
    union { short8 v; unsigned short u[8]; } t;
    t.u[0] = f2bf(a.x); t.u[1] = f2bf(a.y); t.u[2] = f2bf(a.z); t.u[3] = f2bf(a.w);
    t.u[4] = f2bf(b.x); t.u[5] = f2bf(b.y); t.u[6] = f2bf(b.z); t.u[7] = f2bf(b.w);
    *(short8*)&Y[c * 8] = t.v;
}

// ---------------------------------------------------------------------------
// bf16 MFMA GEMM:  C[M,N] fp32 = A[M,K] @ W[N,K]^T, A/W bf16 row-major.
// 128x128 tile, BK=64, 256 threads = 4 waves (2x2), each wave 64x64 out.
// m97-style: global_load_lds width=16 staging, 2-barrier K-loop.
// XOR swizzle: LDS slot s of row r holds col-group s^(r&7) -> 2-way banks on
// frag reads (free) while keeping the lane-linear LDS layout GLD requires.
// ---------------------------------------------------------------------------
#define GBM 128
#define GBN 128
#define GBK 64

__global__ __launch_bounds__(256) void gemm_bf16(const unsigned short* __restrict__ A,
                                                 const unsigned short* __restrict__ W,
                                                 float* __restrict__ C,
                                                 int M, int N, int K) {
    __shared__ unsigned short As[GBM * GBK];   // 16384 B, unpadded
    __shared__ unsigned short Ws[GBN * GBK];   // 16384 B

    const int tid = threadIdx.x;
    const int w = tid >> 6, lane = tid & 63;
    const int l16 = lane & 15, quad = lane >> 4;
    const int wm = (w >> 1) * 64, wn = (w & 1) * 64;
    const int row0 = blockIdx.y * GBM, col0 = blockIdx.x * GBN;

    // staging: wave w stages chunks 4w..4w+3; chunk = 8 rows x 64 cols (1 KB)
    const int rL  = lane >> 3;               // row within chunk (= row&7)
    const int c8g = (lane & 7) ^ rL;         // swizzled col-group this lane fetches
    // fragment-read swizzle (row&7 == l16&7 for all frag rows)
    const int swzk[2] = { (((0 * 4) + quad) ^ (l16 & 7)) * 8,
                          (((1 * 4) + quad) ^ (l16 & 7)) * 8 };

    const float4v zf = {0.f, 0.f, 0.f, 0.f};
    float4v acc[4][4] = {{zf, zf, zf, zf}, {zf, zf, zf, zf},
                         {zf, zf, zf, zf}, {zf, zf, zf, zf}};

    for (int k0 = 0; k0 < K; k0 += GBK) {
        __syncthreads();   // previous compute done; LDS reusable
#pragma unroll
        for (int j = 0; j < 4; ++j) {
            const int ch = w * 4 + j;
            const int r = ch * 8 + rL;
            GLD16(&A[(size_t)(row0 + r) * K + k0 + c8g * 8], &As[ch * 512]);
            GLD16(&W[(size_t)(col0 + r) * K + k0 + c8g * 8], &Ws[ch * 512]);
        }
        __syncthreads();   // drains vmcnt -> tiles ready

#pragma unroll
        for (int kk = 0; kk < 2; ++kk) {
            const int swz = swzk[kk];
            short8 af[4], bf[4];
#pragma unroll
            for (int mi = 0; mi < 4; ++mi)
                af[mi] = *(const short8*)&As[(wm + mi * 16 + l16) * GBK + swz];
#pragma unroll
            for (int ni = 0; ni < 4; ++ni)
                bf[ni] = *(const short8*)&Ws[(wn + ni * 16 + l16) * GBK + swz];
#pragma unroll
            for (int mi = 0; mi < 4; ++mi)
#pragma unroll
                for (int ni = 0; ni < 4; ++ni)
                    acc[mi][ni] = __builtin_amdgcn_mfma_f32_16x16x32_bf16(af[mi], bf[ni], acc[mi][ni], 0, 0, 0);
        }
    }

#pragma unroll
    for (int mi = 0; mi < 4; ++mi)
#pragma unroll
        for (int ni = 0; ni < 4; ++ni)
#pragma unroll
            for (int r = 0; r < 4; ++r)
                C[(size_t)(row0 + wm + mi * 16 + quad * 4 + r) * N + col0 + wn + ni * 16 + l16] =
                    acc[mi][ni][r];
}

// ---------------------------------------------------------------------------
__global__ __launch_bounds__(256) void rmsnorm_b(const float* __restrict__ X,
                                                 const float* __restrict__ w,
                                                 unsigned short* __restrict__ Y,
                                                 int n) {
    __shared__ float tmp[4];
    const int row = blockIdx.x;
    const int tid = threadIdx.x;
    const float* x = X + (size_t)row * n;

    float ss = 0.f;
    for (int c = tid; c < n; c += 256) {
        float v = x[c];
        ss = fmaf(v, v, ss);
    }
#pragma unroll
    for (int off = 32; off; off >>= 1) ss += __shfl_xor(ss, off, 64);
    if ((tid & 63) == 0) tmp[tid >> 6] = ss;
    __syncthreads();
    ss = tmp[0] + tmp[1] + tmp[2] + tmp[3];
    float r = rsqrtf(ss / (float)n + EPSF);

    for (int c = tid; c < n; c += 256)
        Y[(size_t)row * n + c] = f2bf(x[c] * r * w[c]);
}

// ---------------------------------------------------------------------------
__global__ __launch_bounds__(256) void kv_post(const float* __restrict__ KV,
                                               const float* __restrict__ w,
                                               const float* __restrict__ fc,
                                               unsigned short* __restrict__ kvcb,
                                               float* __restrict__ kpe,
                                               int ldkv) {
    __shared__ float tmp[4];
    const int row = blockIdx.x;
    const int s = row & (S_ - 1);
    const int tid = threadIdx.x;
    const float* kv = KV + (size_t)row * ldkv;

    float ss = 0.f;
#pragma unroll
    for (int c = tid; c < KVLORA; c += 256) {
        float v = kv[c];
        ss = fmaf(v, v, ss);
    }
#pragma unroll
    for (int off = 32; off; off >>= 1) ss += __shfl_xor(ss, off, 64);
    if ((tid & 63) == 0) tmp[tid >> 6] = ss;
    __syncthreads();
    ss = tmp[0] + tmp[1] + tmp[2] + tmp[3];
    float r = rsqrtf(ss / (float)KVLORA + EPSF);

#pragma unroll
    for (int c = tid; c < KVLORA; c += 256)
        kvcb[(size_t)row * KVLORA + c] = f2bf(kv[c] * r * w[c]);

    if (tid < 32) {
        int i = tid;
        float c0 = fc[(s * 32 + i) * 2 + 0];
        float s0 = fc[(s * 32 + i) * 2 + 1];
        float x0 = kv[KVLORA + 2 * i];
        float x1 = kv[KVLORA + 2 * i + 1];
        kpe[(size_t)row * DR + 2 * i]     = x0 * c0 - x1 * s0;
        kpe[(size_t)row * DR + 2 * i + 1] = x0 * s0 + x1 * c0;
    }
}

// ---------------------------------------------------------------------------
__global__ __launch_bounds__(256) void q_rope(float* __restrict__ Q,
                                              const float* __restrict__ fc) {
    const int row = blockIdx.x;
    const int s = row & (S_ - 1);
    const int tid = threadIdx.x;
#pragma unroll
    for (int idx = tid; idx < H_ * 32; idx += 256) {
        int h = idx >> 5;
        int i = idx & 31;
        float c0 = fc[(s * 32 + i) * 2 + 0];
        float s0 = fc[(s * 32 + i) * 2 + 1];
        float* qp = Q + (size_t)row * (H_ * DQK) + h * DQK + DN + 2 * i;
        float x0 = qp[0];
        float x1 = qp[1];
        qp[0] = x0 * c0 - x1 * s0;
        qp[1] = x0 * s0 + x1 * c0;
    }
}

// ---------------------------------------------------------------------------
__global__ __launch_bounds__(256) void pack_k(const float* __restrict__ kvb,
                                              const float* __restrict__ kpe,
                                              unsigned short* __restrict__ Kbf) {
    const int c = blockIdx.x * 256 + threadIdx.x;   // chunk of 8 elems
    const int total = B_ * H_ * S_ * (DQK / 8);
    if (c >= total) return;
    const int d8 = c % (DQK / 8);
    const int hs = c / (DQK / 8);
    const int s  = hs % S_;
    const int bh = hs / S_;
    const int b  = bh / H_;
    const int h  = bh % H_;
    const int d  = d8 * 8;
    const int row = b * S_ + s;

    const float* src;
    if (d < DN) src = kvb + (size_t)row * (H_ * 256) + h * 256 + d;
    else        src = kpe + (size_t)row * DR + (d - DN);

    float4 a = *(const float4*)(src);
    float4 bb = *(const float4*)(src + 4);
    union { short8 v; unsigned short u[8]; } t;
    t.u[0] = f2bf(a.x);  t.u[1] = f2bf(a.y);  t.u[2] = f2bf(a.z);  t.u[3] = f2bf(a.w);
    t.u[4] = f2bf(bb.x); t.u[5] = f2bf(bb.y); t.u[6] = f2bf(bb.z); t.u[7] = f2bf(bb.w);
    *(short8*)&Kbf[(size_t)c * 8] = t.v;
}

// ---------------------------------------------------------------------------
__global__ __launch_bounds__(256) void pack_vt(const float* __restrict__ kvb,
                                               unsigned short* __restrict__ Vt) {
    __shared__ unsigned short T[DV][72];
    const int st = blockIdx.x;            // seq tile (64)
    const int bh = blockIdx.y;            // b*H+h
    const int b = bh >> 4, h = bh & 15;
    const int s0 = st * 64;
    const int tid = threadIdx.x;

    for (int c = tid; c < 64 * 16; c += 256) {
        int sp = c >> 4, ch = c & 15;
        const float* src = kvb + (size_t)(b * S_ + s0 + sp) * (H_ * 256) + h * 256 + DN + ch * 8;
        float4 a = *(const float4*)(src);
        float4 bb = *(const float4*)(src + 4);
        int dv = ch * 8;
        T[dv + 0][sp] = f2bf(a.x);  T[dv + 1][sp] = f2bf(a.y);
        T[dv + 2][sp] = f2bf(a.z);  T[dv + 3][sp] = f2bf(a.w);
        T[dv + 4][sp] = f2bf(bb.x); T[dv + 5][sp] = f2bf(bb.y);
        T[dv + 6][sp] = f2bf(bb.z); T[dv + 7][sp] = f2bf(bb.w);
    }
    __syncthreads();
    for (int c = tid; c < 128 * 8; c += 256) {
        int dv = c >> 3, ch = c & 7;
        *(short8*)&Vt[((size_t)bh * DV + dv) * S_ + s0 + ch * 8] = *(short8*)&T[dv][ch * 8];
    }
}

// ---------------------------------------------------------------------------
// MFMA flash attention (causal), bf16 in, fp32 accumulate, bf16 out.
// Work-balanced: block bx handles q-tiles {bx, 31-bx}. Register double-buffer
// prefetch of next K/V tile overlaps HBM latency with compute.
// ---------------------------------------------------------------------------
#define KROW 200    // 192+8 bf16 pad
#define VROW 72     // 64+8
#define PROW 72
#define NQT 32      // 64-row q-tiles per (b,h)

__global__ __launch_bounds__(256, 2) void flash_mfma(const float* __restrict__ Qf,
                                                     const unsigned short* __restrict__ Kbf,
                                                     const unsigned short* __restrict__ Vt,
                                                     unsigned short* __restrict__ Ob) {
    __shared__ unsigned short Ks[64][KROW];     // 25600 B
    __shared__ unsigned short Vs[DV][VROW];     // 18432 B
    __shared__ unsigned short Ps[4][16][PROW];  //  9216 B

    const int bx = blockIdx.x;                  // 0..15 pair index
    const int h = blockIdx.y, b = blockIdx.z;
    const int tid = threadIdx.x;
    const int w = tid >> 6, lane = tid & 63;
    const int l16 = lane & 15, quad = lane >> 4;

    const size_t bh = (size_t)b * H_ + h;
    const unsigned short* Kg = Kbf + bh * S_ * DQK;
    const unsigned short* Vg = Vt + bh * DV * S_;

    for (int half = 0; half < 2; ++half) {
        const int qt = half ? (NQT - 1 - bx) : bx;
        const int q0 = qt * 64;
        const int ntiles = qt + 1;

        // Q A-frags: rows q0+16w+l16, d = i*32 + quad*8
        short8 a_q[6];
        {
            const float* qrow = Qf + (size_t)(b * S_ + q0 + w * 16 + l16) * (H_ * DQK) + h * DQK;
#pragma unroll
            for (int i = 0; i < 6; ++i) {
                const float* p = qrow + i * 32 + quad * 8;
                float4 a = *(const float4*)(p);
                float4 bb = *(const float4*)(p + 4);
                union { short8 v; unsigned short u[8]; } t;
                t.u[0] = f2bf(a.x);  t.u[1] = f2bf(a.y);  t.u[2] = f2bf(a.z);  t.u[3] = f2bf(a.w);
                t.u[4] = f2bf(bb.x); t.u[5] = f2bf(bb.y); t.u[6] = f2bf(bb.z); t.u[7] = f2bf(bb.w);
                a_q[i] = t.v;
            }
        }

        const float4v zf = {0.f, 0.f, 0.f, 0.f};
        float4v o_acc[8] = {zf, zf, zf, zf, zf, zf, zf, zf};
        float m_r[4] = {-1e30f, -1e30f, -1e30f, -1e30f};
        float l_r[4] = {0.f, 0.f, 0.f, 0.f};

        // preload tile 0 into registers
        short8 ldK[6], ldV[4];
#pragma unroll
        for (int i = 0; i < 6; ++i) {
            int c = tid + i * 256;
            int r = c / 24, cc = c % 24;
            ldK[i] = *(const short8*)&Kg[(size_t)r * DQK + cc * 8];
        }
#pragma unroll
        for (int i = 0; i < 4; ++i) {
            int c = tid + i * 256;
            int r = c >> 3, cc = c & 7;
            ldV[i] = *(const short8*)&Vg[(size_t)r * S_ + cc * 8];
        }

        for (int kt = 0; kt < ntiles; ++kt) {
            const int kbase = kt * 64;
            __syncthreads();   // previous compute done; LDS free
#pragma unroll
            for (int i = 0; i < 6; ++i) {
                int c = tid + i * 256;
                int r = c / 24, cc = c % 24;
                *(short8*)&Ks[r][cc * 8] = ldK[i];
            }
#pragma unroll
            for (int i = 0; i < 4; ++i) {
                int c = tid + i * 256;
                int r = c >> 3, cc = c & 7;
                *(short8*)&Vs[r][cc * 8] = ldV[i];
            }
            if (kt + 1 < ntiles) {
                const int kb2 = kbase + 64;
#pragma unroll
                for (int i = 0; i < 6; ++i) {
                    int c = tid + i * 256;
                    int r = c / 24, cc = c % 24;
                    ldK[i] = *(const short8*)&Kg[(size_t)(kb2 + r) * DQK + cc * 8];
                }
#pragma unroll
                for (int i = 0; i < 4; ++i) {
                    int c = tid + i * 256;
                    int r = c >> 3, cc = c & 7;
                    ldV[i] = *(const short8*)&Vg[(size_t)r * S_ + kb2 + cc * 8];
                }
            }
            __syncthreads();   // LDS tile ready

            // QK^T
            float4v sc[4] = {zf, zf, zf, zf};
#pragma unroll
            for (int kg = 0; kg < 4; ++kg) {
#pragma unroll
                for (int i = 0; i < 6; ++i) {
                    short8 bk = *(const short8*)&Ks[kg * 16 + l16][i * 32 + quad * 8];
                    sc[kg] = __builtin_amdgcn_mfma_f32_16x16x32_bf16(a_q[i], bk, sc[kg], 0, 0, 0);
                }
            }

            float scv[4][4];
#pragma unroll
            for (int kg = 0; kg < 4; ++kg)
#pragma unroll
                for (int r = 0; r < 4; ++r)
                    scv[kg][r] = sc[kg][r] * SCALEF;

            if (kt == ntiles - 1) {
#pragma unroll
                for (int kg = 0; kg < 4; ++kg) {
                    int key = kbase + kg * 16 + l16;
#pragma unroll
                    for (int r = 0; r < 4; ++r) {
                        int row = q0 + w * 16 + quad * 4 + r;
                        if (key > row) scv[kg][r] = -1e30f;
                    }
                }
            }

            float mnew[4];
#pragma unroll
            for (int r = 0; r < 4; ++r) {
                float t = fmaxf(fmaxf(scv[0][r], scv[1][r]), fmaxf(scv[2][r], scv[3][r]));
                t = fmaxf(t, __shfl_xor(t, 1));
                t = fmaxf(t, __shfl_xor(t, 2));
                t = fmaxf(t, __shfl_xor(t, 4));
                t = fmaxf(t, __shfl_xor(t, 8));
                mnew[r] = fmaxf(m_r[r], t);
                float a = __expf(m_r[r] - mnew[r]);
                m_r[r] = mnew[r];
                l_r[r] *= a;
#pragma unroll
                for (int dvt = 0; dvt < 8; ++dvt) o_acc[dvt][r] *= a;
            }

            float psum[4] = {0.f, 0.f, 0.f, 0.f};
#pragma unroll
            for (int kg = 0; kg < 4; ++kg)
#pragma unroll
                for (int r = 0; r < 4; ++r) {
                    float p = __expf(scv[kg][r] - mnew[r]);
                    psum[r] += p;
                    Ps[w][quad * 4 + r][kg * 16 + l16] = f2bf(p);
                }
#pragma unroll
            for (int r = 0; r < 4; ++r) {
                float t = psum[r];
                t += __shfl_xor(t, 1);
                t += __shfl_xor(t, 2);
                t += __shfl_xor(t, 4);
                t += __shfl_xor(t, 8);
                l_r[r] += t;
            }

            __syncthreads();   // P writes visible before A-frag reads

            // PV
#pragma unroll
            for (int kc = 0; kc < 2; ++kc) {
                short8 pa = *(const short8*)&Ps[w][l16][kc * 32 + quad * 8];
#pragma unroll
                for (int dvt = 0; dvt < 8; ++dvt) {
                    short8 vb = *(const short8*)&Vs[dvt * 16 + l16][kc * 32 + quad * 8];
                    o_acc[dvt] = __builtin_amdgcn_mfma_f32_16x16x32_bf16(pa, vb, o_acc[dvt], 0, 0, 0);
                }
            }
        }

        // epilogue -> bf16
#pragma unroll
        for (int r = 0; r < 4; ++r) {
            float inv = 1.f / l_r[r];
            int row = q0 + w * 16 + quad * 4 + r;
            unsigned short* op = Ob + (size_t)(b * S_ + row) * (H_ * DV) + h * DV;
#pragma unroll
            for (int dvt = 0; dvt < 8; ++dvt)
                op[dvt * 16 + l16] = f2bf(o_acc[dvt][r] * inv);
        }
    }
}

// ---------------------------------------------------------------------------
extern "C" void kernel_launch(void* const* d_in, const int* in_sizes, int n_in,
                              void* d_out, int out_size, void* d_ws, size_t ws_size,
                              hipStream_t stream) {
    const float* x    = (const float*)d_in[0];
    const float* fc   = (const float*)d_in[1];
    const float* Wqa  = (const float*)d_in[2];
    const float* qlw  = (const float*)d_in[3];
    const float* Wqb  = (const float*)d_in[4];
    const float* Wkva = (const float*)d_in[5];
    const float* kvw  = (const float*)d_in[6];
    const float* Wkvb = (const float*)d_in[7];
    const float* Wo   = (const float*)d_in[8];
    float* out = (float*)d_out;

    const int M = B_ * S_;                 // 4096
    char* wsb = (char*)d_ws;

    // R1: q fp32 (M*3072*4 = 50331648 B)
    float* q = (float*)wsb;
    // R2 (67108864 B): early-phase residents, dead before kvb write
    char* R2 = wsb + 50331648;
    float*          qlat  = (float*)R2;                          // 25165824 B
    unsigned short* xb    = (unsigned short*)(R2 + 25165824);    // 16777216 B
    unsigned short* Wqab  = (unsigned short*)(R2 + 41943040);    //  6291456 B
    unsigned short* Wkvab = (unsigned short*)(R2 + 48234496);    //  2621440 B
    unsigned short* Wqbb  = (unsigned short*)(R2 + 50855936);    //  9437184 B
    float*          kvb   = (float*)R2;                          // step 8
    unsigned short* attnb = (unsigned short*)R2;                 // step 10
    // R3 (25165824 B)
    char* R3 = R2 + 67108864;
    float*          kvraw = (float*)R3;                          // 10485760 B
    unsigned short* qlatb = (unsigned short*)(R3 + 10485760);    // 12582912 B
    unsigned short* Kbf   = (unsigned short*)R3;                 // step 9
    unsigned short* Wob   = (unsigned short*)R3;                 // after flash
    // R4 (16777216 B)
    char* R4 = R3 + 25165824;
    float*          kpe   = (float*)R4;                          //  1048576 B
    unsigned short* kvcb  = (unsigned short*)(R4 + 1048576);     //  4194304 B
    unsigned short* Wkvbb = (unsigned short*)(R4 + 5242880);     //  4194304 B
    unsigned short* Vt    = (unsigned short*)R4;                 // step 9 (after pack_k!)

    // 0) bf16 conversions
    conv_b<<<(M * D_) / 2048, 256, 0, stream>>>(x, xb);
    conv_b<<<(QLORA * D_) / 2048, 256, 0, stream>>>(Wqa, Wqab);
    conv_b<<<(576 * D_) / 2048, 256, 0, stream>>>(Wkva, Wkvab);
    conv_b<<<(H_ * DQK * QLORA) / 2048, 256, 0, stream>>>(Wqb, Wqbb);
    conv_b<<<(H_ * 256 * KVLORA) / 2048, 256, 0, stream>>>(Wkvb, Wkvbb);

    // 1) qlat = xb @ Wqab^T ; kvraw = xb @ Wkvab^T (N padded to 640)
    gemm_bf16<<<dim3(QLORA / GBN, M / GBM), 256, 0, stream>>>(xb, Wqab, qlat, M, QLORA, D_);
    gemm_bf16<<<dim3(640 / GBN, M / GBM), 256, 0, stream>>>(xb, Wkvab, kvraw, M, 640, D_);

    // 2) norms (emit bf16) + k_pe rope
    rmsnorm_b<<<M, 256, 0, stream>>>(qlat, qlw, qlatb, QLORA);
    kv_post<<<M, 256, 0, stream>>>(kvraw, kvw, fc, kvcb, kpe, 640);

    // 3) q = qlatb @ Wqbb^T ; rope q_pe ; kvb = kvcb @ Wkvbb^T
    gemm_bf16<<<dim3(H_ * DQK / GBN, M / GBM), 256, 0, stream>>>(qlatb, Wqbb, q, M, H_ * DQK, QLORA);
    q_rope<<<M, 256, 0, stream>>>(q, fc);
    gemm_bf16<<<dim3(H_ * 256 / GBN, M / GBM), 256, 0, stream>>>(kvcb, Wkvbb, kvb, M, H_ * 256, KVLORA);

    // 4) pack K then V (pack_k reads kpe which Vt overwrites -> strict order)
    {
        int total = B_ * H_ * S_ * (DQK / 8);
        pack_k<<<(total + 255) / 256, 256, 0, stream>>>(kvb, kpe, Kbf);
        pack_vt<<<dim3(S_ / 64, B_ * H_), 256, 0, stream>>>(kvb, Vt);
    }

    // 5) MFMA flash attention (work-balanced pairs) -> bf16 attn
    flash_mfma<<<dim3(NQT / 2, H_, B_), 256, 0, stream>>>(q, Kbf, Vt, attnb);

    // 6) convert Wo (into dead Kbf region) and final GEMM
    conv_b<<<(D_ * H_ * DV) / 2048, 256, 0, stream>>>(Wo, Wob);
    gemm_bf16<<<dim3(D_ / GBN, M / GBM), 256, 0, stream>>>(attnb, Wob, out, M, D_, D_);
}